// Round 10
// baseline (963.456 us; speedup 1.0000x reference)
//
#include <hip/hip_runtime.h>

#define THREADS 256

__device__ __forceinline__ float ftanh(float x) {
    x = fminf(9.0f, fmaxf(-9.0f, x));
    float t = __expf(2.0f * x);
    return (t - 1.0f) * __builtin_amdgcn_rcpf(t + 1.0f);
}

__device__ __forceinline__ int clampi(int v, int lo, int hi) {
    return v < lo ? lo : (v > hi ? hi : v);
}

// ---------------- CSR build: histogram -> scan -> scatter(packed rc) ----------------

__global__ __launch_bounds__(THREADS) void hist_kernel(
    const int* __restrict__ row, int* __restrict__ cnt, int E, int N)
{
    int e = blockIdx.x * THREADS + threadIdx.x;
    if (e < E) {
        int r = row[e];
        if ((unsigned)r < (unsigned)N) atomicAdd(&cnt[r], 1);
    }
}

// one block of 256 threads: exclusive scan of cnt[N] -> start[N]
__global__ __launch_bounds__(THREADS) void scan_kernel(
    const int* __restrict__ cnt, int* __restrict__ start, int N)
{
    __shared__ int ssum[THREADS];
    int t = threadIdx.x;
    int chunk = (N + THREADS - 1) / THREADS;
    int lo = t * chunk, hi = min(lo + chunk, N);
    int s = 0;
    for (int i = lo; i < hi; ++i) s += cnt[i];
    ssum[t] = s;
    __syncthreads();
    for (int d = 1; d < THREADS; d <<= 1) {
        int v = (t >= d) ? ssum[t - d] : 0;
        __syncthreads();
        ssum[t] += v;
        __syncthreads();
    }
    int base = (t == 0) ? 0 : ssum[t - 1];
    for (int i = lo; i < hi; ++i) { start[i] = base; base += cnt[i]; }
}

// bump start[] in place; rc[pos] = (row<<16)|col packed (requires N <= 65535).
// All writes bounds-checked.
__global__ __launch_bounds__(THREADS) void scatter_rc_kernel(
    const int* __restrict__ row, const int* __restrict__ col,
    int* __restrict__ start, int* __restrict__ rc, int E, int N)
{
    int e = blockIdx.x * THREADS + threadIdx.x;
    if (e < E) {
        int r = row[e];
        if ((unsigned)r < (unsigned)N) {
            int pos = atomicAdd(&start[r], 1);
            if ((unsigned)pos < (unsigned)E) {
                int c = clampi(col[e], 0, N - 1);
                rc[pos] = (int)(((unsigned)r << 16) | (unsigned)c);
            }
        }
    }
}

// ---------------- edge MLP (sorted, packed rc stream) + wave-segmented reduce ----------------
// __launch_bounds__(256, 4): 4 waves/EU -> allocator may use up to 128 VGPRs.
// Working set (x[33]+acc[32]+temps ~100 floats) spilled to scratch at the
// default 60-VGPR allocation; 128 VGPRs eliminates spills.

__global__ __launch_bounds__(THREADS, 4) void edge_kernel_sorted(
    const int* __restrict__ rc,
    const float* __restrict__ coord, const float* __restrict__ h,
    const float* __restrict__ Wm1, const float* __restrict__ bm1,
    const float* __restrict__ Wm2, const float* __restrict__ bm2,
    const float* __restrict__ Wc1, const float* __restrict__ bc1,
    const float* __restrict__ Wc2,
    float* __restrict__ num, float* __restrict__ agg, int E, int N)
{
    __shared__ float sWm1[33 * 32];
    __shared__ float sWm2[32 * 32];
    __shared__ float sWc1[32 * 32];
    __shared__ float sbm1[32], sbm2[32], sbc1[32], sWc2[32];

    for (int i = threadIdx.x; i < 33 * 32; i += THREADS) sWm1[i] = Wm1[i];
    for (int i = threadIdx.x; i < 32 * 32; i += THREADS) sWm2[i] = Wm2[i];
    for (int i = threadIdx.x; i < 32 * 32; i += THREADS) sWc1[i] = Wc1[i];
    if (threadIdx.x < 32) {
        sbm1[threadIdx.x] = bm1[threadIdx.x];
        sbm2[threadIdx.x] = bm2[threadIdx.x];
        sbc1[threadIdx.x] = bc1[threadIdx.x];
        sWc2[threadIdx.x] = Wc2[threadIdx.x];
    }
    __syncthreads();

    int e = blockIdx.x * THREADS + threadIdx.x;
    int lane = threadIdx.x & 63;

    int r = 0, c = 0, seg = -1;
    if (e < E) {
        // sequential single-use stream: nontemporal so it doesn't evict h/coord from L2
        unsigned p = (unsigned)__builtin_nontemporal_load(&rc[e]);
        r = clampi((int)(p >> 16), 0, N - 1);
        c = clampi((int)(p & 0xFFFFu), 0, N - 1);
        seg = r;
    }

    float rx = coord[(size_t)r * 3 + 0] - coord[(size_t)c * 3 + 0];
    float ry = coord[(size_t)r * 3 + 1] - coord[(size_t)c * 3 + 1];
    float rz = coord[(size_t)r * 3 + 2] - coord[(size_t)c * 3 + 2];
    float d2 = rx * rx + ry * ry + rz * rz;

    float x[33];
    {
        const float4* hr = (const float4*)(h + (size_t)r * 16);
        const float4* hc = (const float4*)(h + (size_t)c * 16);
#pragma unroll
        for (int q = 0; q < 4; ++q) {
            float4 a = hr[q];
            x[4 * q + 0] = a.x; x[4 * q + 1] = a.y;
            x[4 * q + 2] = a.z; x[4 * q + 3] = a.w;
        }
#pragma unroll
        for (int q = 0; q < 4; ++q) {
            float4 b = hc[q];
            x[16 + 4 * q + 0] = b.x; x[16 + 4 * q + 1] = b.y;
            x[16 + 4 * q + 2] = b.z; x[16 + 4 * q + 3] = b.w;
        }
        x[32] = d2;
    }

    float acc[32];
#pragma unroll
    for (int j = 0; j < 32; ++j) acc[j] = sbm1[j];
#pragma unroll
    for (int k = 0; k < 33; ++k) {
        float xk = x[k];
        const float4* w4 = (const float4*)(sWm1 + k * 32);
#pragma unroll
        for (int q = 0; q < 8; ++q) {
            float4 w = w4[q];
            acc[4 * q + 0] = fmaf(xk, w.x, acc[4 * q + 0]);
            acc[4 * q + 1] = fmaf(xk, w.y, acc[4 * q + 1]);
            acc[4 * q + 2] = fmaf(xk, w.z, acc[4 * q + 2]);
            acc[4 * q + 3] = fmaf(xk, w.w, acc[4 * q + 3]);
        }
    }
    float t1[32];
#pragma unroll
    for (int j = 0; j < 32; ++j) t1[j] = ftanh(acc[j]);

#pragma unroll
    for (int j = 0; j < 32; ++j) acc[j] = sbm2[j];
#pragma unroll
    for (int k = 0; k < 32; ++k) {
        float xk = t1[k];
        const float4* w4 = (const float4*)(sWm2 + k * 32);
#pragma unroll
        for (int q = 0; q < 8; ++q) {
            float4 w = w4[q];
            acc[4 * q + 0] = fmaf(xk, w.x, acc[4 * q + 0]);
            acc[4 * q + 1] = fmaf(xk, w.y, acc[4 * q + 1]);
            acc[4 * q + 2] = fmaf(xk, w.z, acc[4 * q + 2]);
            acc[4 * q + 3] = fmaf(xk, w.w, acc[4 * q + 3]);
        }
    }

    float v[35];
#pragma unroll
    for (int j = 0; j < 32; ++j) v[j] = ftanh(acc[j]);

#pragma unroll
    for (int j = 0; j < 32; ++j) acc[j] = sbc1[j];
#pragma unroll
    for (int k = 0; k < 32; ++k) {
        float xk = v[k];
        const float4* w4 = (const float4*)(sWc1 + k * 32);
#pragma unroll
        for (int q = 0; q < 8; ++q) {
            float4 w = w4[q];
            acc[4 * q + 0] = fmaf(xk, w.x, acc[4 * q + 0]);
            acc[4 * q + 1] = fmaf(xk, w.y, acc[4 * q + 1]);
            acc[4 * q + 2] = fmaf(xk, w.z, acc[4 * q + 2]);
            acc[4 * q + 3] = fmaf(xk, w.w, acc[4 * q + 3]);
        }
    }
    float cw = 0.0f;
#pragma unroll
    for (int j = 0; j < 32; ++j) cw = fmaf(ftanh(acc[j]), sWc2[j], cw);
    cw = ftanh(cw);

    float s = cw * __builtin_amdgcn_rcpf(__builtin_amdgcn_sqrtf(d2) + 1.0f);
    v[32] = rx * s; v[33] = ry * s; v[34] = rz * s;

    // wave-level segmented inclusive scan; rows contiguous after sort.
#define SEGSTEP(D)                                                \
    {                                                             \
        int rup = __shfl_up(seg, D);                              \
        bool ok = (lane >= D) && (rup == seg);                    \
        _Pragma("unroll")                                         \
        for (int k = 0; k < 35; ++k) {                            \
            float o = __shfl_up(v[k], D);                         \
            v[k] += ok ? o : 0.0f;                                \
        }                                                         \
    }
    SEGSTEP(1) SEGSTEP(2) SEGSTEP(4) SEGSTEP(8) SEGSTEP(16) SEGSTEP(32)
#undef SEGSTEP

    int rdn = __shfl_down(seg, 1);
    bool tail = (lane == 63) || (rdn != seg);
    if (tail && seg >= 0) {
        float* ar = agg + (size_t)seg * 32;
#pragma unroll
        for (int k = 0; k < 32; ++k) atomicAdd(ar + k, v[k]);
        float* nr = num + (size_t)seg * 3;
        atomicAdd(nr + 0, v[32]);
        atomicAdd(nr + 1, v[33]);
        atomicAdd(nr + 2, v[34]);
    }
}

// ---------------- fallback: per-edge atomics (round-1, proven) ----------------

__global__ __launch_bounds__(THREADS, 4) void edge_kernel_naive(
    const int* __restrict__ row, const int* __restrict__ col,
    const float* __restrict__ coord, const float* __restrict__ h,
    const float* __restrict__ Wm1, const float* __restrict__ bm1,
    const float* __restrict__ Wm2, const float* __restrict__ bm2,
    const float* __restrict__ Wc1, const float* __restrict__ bc1,
    const float* __restrict__ Wc2,
    float* __restrict__ num, float* __restrict__ agg, int E, int N)
{
    __shared__ float sWm1[33 * 32];
    __shared__ float sWm2[32 * 32];
    __shared__ float sWc1[32 * 32];
    __shared__ float sbm1[32], sbm2[32], sbc1[32], sWc2[32];

    for (int i = threadIdx.x; i < 33 * 32; i += THREADS) sWm1[i] = Wm1[i];
    for (int i = threadIdx.x; i < 32 * 32; i += THREADS) sWm2[i] = Wm2[i];
    for (int i = threadIdx.x; i < 32 * 32; i += THREADS) sWc1[i] = Wc1[i];
    if (threadIdx.x < 32) {
        sbm1[threadIdx.x] = bm1[threadIdx.x];
        sbm2[threadIdx.x] = bm2[threadIdx.x];
        sbc1[threadIdx.x] = bc1[threadIdx.x];
        sWc2[threadIdx.x] = Wc2[threadIdx.x];
    }
    __syncthreads();

    int e = blockIdx.x * THREADS + threadIdx.x;
    if (e >= E) return;

    int r = clampi(row[e], 0, N - 1);
    int c = clampi(col[e], 0, N - 1);

    float rx = coord[(size_t)r * 3 + 0] - coord[(size_t)c * 3 + 0];
    float ry = coord[(size_t)r * 3 + 1] - coord[(size_t)c * 3 + 1];
    float rz = coord[(size_t)r * 3 + 2] - coord[(size_t)c * 3 + 2];
    float d2 = rx * rx + ry * ry + rz * rz;

    float x[33];
    {
        const float4* hr = (const float4*)(h + (size_t)r * 16);
        const float4* hc = (const float4*)(h + (size_t)c * 16);
#pragma unroll
        for (int q = 0; q < 4; ++q) {
            float4 a = hr[q];
            x[4 * q + 0] = a.x; x[4 * q + 1] = a.y;
            x[4 * q + 2] = a.z; x[4 * q + 3] = a.w;
        }
#pragma unroll
        for (int q = 0; q < 4; ++q) {
            float4 b = hc[q];
            x[16 + 4 * q + 0] = b.x; x[16 + 4 * q + 1] = b.y;
            x[16 + 4 * q + 2] = b.z; x[16 + 4 * q + 3] = b.w;
        }
        x[32] = d2;
    }

    float acc[32];
#pragma unroll
    for (int j = 0; j < 32; ++j) acc[j] = sbm1[j];
#pragma unroll
    for (int k = 0; k < 33; ++k) {
        float xk = x[k];
        const float4* w4 = (const float4*)(sWm1 + k * 32);
#pragma unroll
        for (int q = 0; q < 8; ++q) {
            float4 w = w4[q];
            acc[4 * q + 0] = fmaf(xk, w.x, acc[4 * q + 0]);
            acc[4 * q + 1] = fmaf(xk, w.y, acc[4 * q + 1]);
            acc[4 * q + 2] = fmaf(xk, w.z, acc[4 * q + 2]);
            acc[4 * q + 3] = fmaf(xk, w.w, acc[4 * q + 3]);
        }
    }
    float t1[32];
#pragma unroll
    for (int j = 0; j < 32; ++j) t1[j] = ftanh(acc[j]);

#pragma unroll
    for (int j = 0; j < 32; ++j) acc[j] = sbm2[j];
#pragma unroll
    for (int k = 0; k < 32; ++k) {
        float xk = t1[k];
        const float4* w4 = (const float4*)(sWm2 + k * 32);
#pragma unroll
        for (int q = 0; q < 8; ++q) {
            float4 w = w4[q];
            acc[4 * q + 0] = fmaf(xk, w.x, acc[4 * q + 0]);
            acc[4 * q + 1] = fmaf(xk, w.y, acc[4 * q + 1]);
            acc[4 * q + 2] = fmaf(xk, w.z, acc[4 * q + 2]);
            acc[4 * q + 3] = fmaf(xk, w.w, acc[4 * q + 3]);
        }
    }
    float m[32];
#pragma unroll
    for (int j = 0; j < 32; ++j) m[j] = ftanh(acc[j]);

#pragma unroll
    for (int j = 0; j < 32; ++j) acc[j] = sbc1[j];
#pragma unroll
    for (int k = 0; k < 32; ++k) {
        float xk = m[k];
        const float4* w4 = (const float4*)(sWc1 + k * 32);
#pragma unroll
        for (int q = 0; q < 8; ++q) {
            float4 w = w4[q];
            acc[4 * q + 0] = fmaf(xk, w.x, acc[4 * q + 0]);
            acc[4 * q + 1] = fmaf(xk, w.y, acc[4 * q + 1]);
            acc[4 * q + 2] = fmaf(xk, w.z, acc[4 * q + 2]);
            acc[4 * q + 3] = fmaf(xk, w.w, acc[4 * q + 3]);
        }
    }
    float cw = 0.0f;
#pragma unroll
    for (int j = 0; j < 32; ++j) cw = fmaf(ftanh(acc[j]), sWc2[j], cw);
    cw = ftanh(cw);

    float s = cw * __builtin_amdgcn_rcpf(__builtin_amdgcn_sqrtf(d2) + 1.0f);

    float* nr = num + (size_t)r * 3;
    atomicAdd(nr + 0, rx * s);
    atomicAdd(nr + 1, ry * s);
    atomicAdd(nr + 2, rz * s);
    float* ar = agg + (size_t)r * 32;
#pragma unroll
    for (int k = 0; k < 32; ++k) atomicAdd(ar + k, m[k]);
}

// ---------------- node update ----------------

__global__ __launch_bounds__(THREADS, 4) void node_kernel(
    const float* __restrict__ coord_in, const float* __restrict__ h_in,
    const float* __restrict__ num, const float* __restrict__ agg,
    const int* __restrict__ cnt, const float* __restrict__ mask,
    const float* __restrict__ Wn1, const float* __restrict__ bn1,
    const float* __restrict__ Wn2, const float* __restrict__ bn2,
    float* __restrict__ coord_out, float* __restrict__ h_out, int N)
{
    __shared__ float sWn1[48 * 32];
    __shared__ float sWn2[32 * 16];
    __shared__ float sbn1[32], sbn2[16];

    for (int i = threadIdx.x; i < 48 * 32; i += THREADS) sWn1[i] = Wn1[i];
    for (int i = threadIdx.x; i < 32 * 16; i += THREADS) sWn2[i] = Wn2[i];
    if (threadIdx.x < 32) sbn1[threadIdx.x] = bn1[threadIdx.x];
    if (threadIdx.x < 16) sbn2[threadIdx.x] = bn2[threadIdx.x];
    __syncthreads();

    int i = blockIdx.x * THREADS + threadIdx.x;
    if (i >= N) return;

    float msk = mask[i];
    float inv_cnt = __builtin_amdgcn_rcpf(fmaxf((float)cnt[i], 1.0f));

#pragma unroll
    for (int dd = 0; dd < 3; ++dd) {
        float cv = coord_in[(size_t)i * 3 + dd];
        float ov = cv + num[(size_t)i * 3 + dd] * inv_cnt;
        coord_out[(size_t)i * 3 + dd] = ov * msk + cv * (1.0f - msk);
    }

    float hv[16];
    float x[48];
    {
        const float4* hp = (const float4*)(h_in + (size_t)i * 16);
#pragma unroll
        for (int q = 0; q < 4; ++q) {
            float4 a = hp[q];
            hv[4 * q + 0] = a.x; hv[4 * q + 1] = a.y;
            hv[4 * q + 2] = a.z; hv[4 * q + 3] = a.w;
            x[4 * q + 0] = a.x; x[4 * q + 1] = a.y;
            x[4 * q + 2] = a.z; x[4 * q + 3] = a.w;
        }
        const float4* ap = (const float4*)(agg + (size_t)i * 32);
#pragma unroll
        for (int q = 0; q < 8; ++q) {
            float4 a = ap[q];
            x[16 + 4 * q + 0] = a.x; x[16 + 4 * q + 1] = a.y;
            x[16 + 4 * q + 2] = a.z; x[16 + 4 * q + 3] = a.w;
        }
    }

    float acc[32];
#pragma unroll
    for (int j = 0; j < 32; ++j) acc[j] = sbn1[j];
#pragma unroll
    for (int k = 0; k < 48; ++k) {
        float xk = x[k];
        const float4* w4 = (const float4*)(sWn1 + k * 32);
#pragma unroll
        for (int q = 0; q < 8; ++q) {
            float4 w = w4[q];
            acc[4 * q + 0] = fmaf(xk, w.x, acc[4 * q + 0]);
            acc[4 * q + 1] = fmaf(xk, w.y, acc[4 * q + 1]);
            acc[4 * q + 2] = fmaf(xk, w.z, acc[4 * q + 2]);
            acc[4 * q + 3] = fmaf(xk, w.w, acc[4 * q + 3]);
        }
    }
    float t[32];
#pragma unroll
    for (int j = 0; j < 32; ++j) t[j] = ftanh(acc[j]);

    float acc2[16];
#pragma unroll
    for (int j = 0; j < 16; ++j) acc2[j] = sbn2[j];
#pragma unroll
    for (int k = 0; k < 32; ++k) {
        float xk = t[k];
        const float4* w4 = (const float4*)(sWn2 + k * 16);
#pragma unroll
        for (int q = 0; q < 4; ++q) {
            float4 w = w4[q];
            acc2[4 * q + 0] = fmaf(xk, w.x, acc2[4 * q + 0]);
            acc2[4 * q + 1] = fmaf(xk, w.y, acc2[4 * q + 1]);
            acc2[4 * q + 2] = fmaf(xk, w.z, acc2[4 * q + 2]);
            acc2[4 * q + 3] = fmaf(xk, w.w, acc2[4 * q + 3]);
        }
    }

    float hn[16];
    float mean = 0.0f;
#pragma unroll
    for (int j = 0; j < 16; ++j) { hn[j] = hv[j] + acc2[j]; mean += hn[j]; }
    mean *= (1.0f / 16.0f);
    float var = 0.0f;
#pragma unroll
    for (int j = 0; j < 16; ++j) { float d = hn[j] - mean; var = fmaf(d, d, var); }
    var *= (1.0f / 16.0f);
    float stdv = __builtin_amdgcn_sqrtf(var + 1e-5f);
    float sc = __builtin_amdgcn_rsqf(stdv);   // (var+eps)^(-1/4)

#pragma unroll
    for (int j = 0; j < 16; ++j) {
        h_out[(size_t)i * 16 + j] = hn[j] * sc * msk + hv[j] * (1.0f - msk);
    }
}

extern "C" void kernel_launch(void* const* d_in, const int* in_sizes, int n_in,
                              void* d_out, int out_size, void* d_ws, size_t ws_size,
                              hipStream_t stream) {
    const int*   edge_index = (const int*)d_in[0];
    const float* coord      = (const float*)d_in[1];
    const float* h          = (const float*)d_in[2];
    const float* fire       = (const float*)d_in[3];
    const float* Wm1 = (const float*)d_in[4];
    const float* bm1 = (const float*)d_in[5];
    const float* Wm2 = (const float*)d_in[6];
    const float* bm2 = (const float*)d_in[7];
    const float* Wc1 = (const float*)d_in[8];
    const float* bc1 = (const float*)d_in[9];
    const float* Wc2 = (const float*)d_in[10];
    const float* Wn1 = (const float*)d_in[11];
    const float* bn1 = (const float*)d_in[12];
    const float* Wn2 = (const float*)d_in[13];
    const float* bn2 = (const float*)d_in[14];

    const int E = in_sizes[0] / 2;
    const int N = in_sizes[1] / 3;
    const int* row = edge_index;
    const int* col = edge_index + E;

    // ws layout: num 3N f32 | agg 32N f32 | cnth N i32 | startA N i32 | rc E i32
    float* ws     = (float*)d_ws;
    float* num    = ws;
    float* agg    = ws + (size_t)N * 3;
    int*   cnth   = (int*)(ws + (size_t)N * 35);
    int*   startA = cnth + N;
    int*   rc     = startA + N;

    float* out_coord = (float*)d_out;
    float* out_h     = (float*)d_out + (size_t)N * 3;

    const int eb = (E + THREADS - 1) / THREADS;
    const int nb = (N + THREADS - 1) / THREADS;

    const size_t need_sorted = ((size_t)N * 37 + (size_t)E) * sizeof(float) + (1u << 20);

    if (ws_size >= need_sorted && N <= 65535) {
        // ---- one-time CSR build with packed (row<<16|col) stream ----
        hipMemsetAsync(d_ws, 0, (size_t)N * 36 * sizeof(float), stream);
        hist_kernel<<<eb, THREADS, 0, stream>>>(row, cnth, E, N);
        scan_kernel<<<1, THREADS, 0, stream>>>(cnth, startA, N);
        scatter_rc_kernel<<<eb, THREADS, 0, stream>>>(row, col, startA, rc, E, N);

        edge_kernel_sorted<<<eb, THREADS, 0, stream>>>(rc, coord, h,
            Wm1, bm1, Wm2, bm2, Wc1, bc1, Wc2, num, agg, E, N);
        node_kernel<<<nb, THREADS, 0, stream>>>(coord, h, num, agg, cnth, fire,
            Wn1, bn1, Wn2, bn2, out_coord, out_h, N);

        hipMemsetAsync(num, 0, (size_t)N * 35 * sizeof(float), stream);
        edge_kernel_sorted<<<eb, THREADS, 0, stream>>>(rc, out_coord, out_h,
            Wm1, bm1, Wm2, bm2, Wc1, bc1, Wc2, num, agg, E, N);
        node_kernel<<<nb, THREADS, 0, stream>>>(out_coord, out_h, num, agg, cnth, fire + N,
            Wn1, bn1, Wn2, bn2, out_coord, out_h, N);
    } else {
        // ---- fallback: proven round-1 atomic path (7.2 MB) ----
        hipMemsetAsync(d_ws, 0, (size_t)N * 36 * sizeof(float), stream);
        hist_kernel<<<eb, THREADS, 0, stream>>>(row, cnth, E, N);

        edge_kernel_naive<<<eb, THREADS, 0, stream>>>(row, col, coord, h,
            Wm1, bm1, Wm2, bm2, Wc1, bc1, Wc2, num, agg, E, N);
        node_kernel<<<nb, THREADS, 0, stream>>>(coord, h, num, agg, cnth, fire,
            Wn1, bn1, Wn2, bn2, out_coord, out_h, N);

        hipMemsetAsync(num, 0, (size_t)N * 35 * sizeof(float), stream);
        edge_kernel_naive<<<eb, THREADS, 0, stream>>>(row, col, out_coord, out_h,
            Wm1, bm1, Wm2, bm2, Wc1, bc1, Wc2, num, agg, E, N);
        node_kernel<<<nb, THREADS, 0, stream>>>(out_coord, out_h, num, agg, cnth, fire + N,
            Wn1, bn1, Wn2, bn2, out_coord, out_h, N);
    }
}

// Round 11
// 736.286 us; speedup vs baseline: 1.3085x; 1.3085x over previous
//
#include <hip/hip_runtime.h>

#define THREADS 256

// clamp-free fast tanh: 1 - 2/(e^2x + 1).
// t=+inf -> rcp=0 -> 1; t=0 -> -1. No inf*0 NaN path, so no clamp needed.
__device__ __forceinline__ float ftanh(float x) {
    float t = __expf(2.0f * x);
    return fmaf(-2.0f, __builtin_amdgcn_rcpf(t + 1.0f), 1.0f);
}

__device__ __forceinline__ int clampi(int v, int lo, int hi) {
    return v < lo ? lo : (v > hi ? hi : v);
}

// ---------------- CSR build: histogram -> scan -> scatter(packed rc) ----------------

__global__ __launch_bounds__(THREADS) void hist_kernel(
    const int* __restrict__ row, int* __restrict__ cnt, int E, int N)
{
    int e = blockIdx.x * THREADS + threadIdx.x;
    if (e < E) {
        int r = row[e];
        if ((unsigned)r < (unsigned)N) atomicAdd(&cnt[r], 1);
    }
}

// one block of 256 threads: exclusive scan of cnt[N] -> start[N]
__global__ __launch_bounds__(THREADS) void scan_kernel(
    const int* __restrict__ cnt, int* __restrict__ start, int N)
{
    __shared__ int ssum[THREADS];
    int t = threadIdx.x;
    int chunk = (N + THREADS - 1) / THREADS;
    int lo = t * chunk, hi = min(lo + chunk, N);
    int s = 0;
    for (int i = lo; i < hi; ++i) s += cnt[i];
    ssum[t] = s;
    __syncthreads();
    for (int d = 1; d < THREADS; d <<= 1) {
        int v = (t >= d) ? ssum[t - d] : 0;
        __syncthreads();
        ssum[t] += v;
        __syncthreads();
    }
    int base = (t == 0) ? 0 : ssum[t - 1];
    for (int i = lo; i < hi; ++i) { start[i] = base; base += cnt[i]; }
}

// bump start[] in place; rc[pos] = (row<<16)|col packed (requires N <= 65535).
// All writes bounds-checked.
__global__ __launch_bounds__(THREADS) void scatter_rc_kernel(
    const int* __restrict__ row, const int* __restrict__ col,
    int* __restrict__ start, int* __restrict__ rc, int E, int N)
{
    int e = blockIdx.x * THREADS + threadIdx.x;
    if (e < E) {
        int r = row[e];
        if ((unsigned)r < (unsigned)N) {
            int pos = atomicAdd(&start[r], 1);
            if ((unsigned)pos < (unsigned)E) {
                int c = clampi(col[e], 0, N - 1);
                rc[pos] = (int)(((unsigned)r << 16) | (unsigned)c);
            }
        }
    }
}

// ---------------- edge MLP (sorted, packed rc stream) + wave-segmented reduce ----------------
// Weights are read DIRECTLY from global with wave-uniform compile-time indices:
// hipcc scalarizes these to s_load (SMEM pipe, L1-resident 13 KB) and emits
// v_fmac with an SGPR weight operand. This removes the 776 ds_read_b128/wave
// that LDS staging cost (LDS has no scalar path for wave-uniform data).
// No __shared__ in this kernel; the only LDS-pipe traffic left is the scan's
// ds_bpermute. Body is branch-free (no early return) so loads stay uniform.

__global__ __launch_bounds__(THREADS, 4) void edge_kernel_sorted(
    const int* __restrict__ rc,
    const float* __restrict__ coord, const float* __restrict__ h,
    const float* __restrict__ Wm1, const float* __restrict__ bm1,
    const float* __restrict__ Wm2, const float* __restrict__ bm2,
    const float* __restrict__ Wc1, const float* __restrict__ bc1,
    const float* __restrict__ Wc2,
    float* __restrict__ num, float* __restrict__ agg, int E, int N)
{
    int e = blockIdx.x * THREADS + threadIdx.x;
    int lane = threadIdx.x & 63;

    int r = 0, c = 0, seg = -1;
    if (e < E) {
        // sequential single-use stream: nontemporal so it doesn't evict h/coord from L2
        unsigned p = (unsigned)__builtin_nontemporal_load(&rc[e]);
        r = clampi((int)(p >> 16), 0, N - 1);
        c = clampi((int)(p & 0xFFFFu), 0, N - 1);
        seg = r;
    }

    float rx = coord[(size_t)r * 3 + 0] - coord[(size_t)c * 3 + 0];
    float ry = coord[(size_t)r * 3 + 1] - coord[(size_t)c * 3 + 1];
    float rz = coord[(size_t)r * 3 + 2] - coord[(size_t)c * 3 + 2];
    float d2 = rx * rx + ry * ry + rz * rz;

    float x[33];
    {
        const float4* hr = (const float4*)(h + (size_t)r * 16);
        const float4* hc = (const float4*)(h + (size_t)c * 16);
#pragma unroll
        for (int q = 0; q < 4; ++q) {
            float4 a = hr[q];
            x[4 * q + 0] = a.x; x[4 * q + 1] = a.y;
            x[4 * q + 2] = a.z; x[4 * q + 3] = a.w;
        }
#pragma unroll
        for (int q = 0; q < 4; ++q) {
            float4 b = hc[q];
            x[16 + 4 * q + 0] = b.x; x[16 + 4 * q + 1] = b.y;
            x[16 + 4 * q + 2] = b.z; x[16 + 4 * q + 3] = b.w;
        }
        x[32] = d2;
    }

    float acc[32];
#pragma unroll
    for (int j = 0; j < 32; ++j) acc[j] = bm1[j];
#pragma unroll
    for (int k = 0; k < 33; ++k) {
        float xk = x[k];
        const float4* w4 = (const float4*)(Wm1 + k * 32);
#pragma unroll
        for (int q = 0; q < 8; ++q) {
            float4 w = w4[q];
            acc[4 * q + 0] = fmaf(xk, w.x, acc[4 * q + 0]);
            acc[4 * q + 1] = fmaf(xk, w.y, acc[4 * q + 1]);
            acc[4 * q + 2] = fmaf(xk, w.z, acc[4 * q + 2]);
            acc[4 * q + 3] = fmaf(xk, w.w, acc[4 * q + 3]);
        }
    }
    float t1[32];
#pragma unroll
    for (int j = 0; j < 32; ++j) t1[j] = ftanh(acc[j]);

#pragma unroll
    for (int j = 0; j < 32; ++j) acc[j] = bm2[j];
#pragma unroll
    for (int k = 0; k < 32; ++k) {
        float xk = t1[k];
        const float4* w4 = (const float4*)(Wm2 + k * 32);
#pragma unroll
        for (int q = 0; q < 8; ++q) {
            float4 w = w4[q];
            acc[4 * q + 0] = fmaf(xk, w.x, acc[4 * q + 0]);
            acc[4 * q + 1] = fmaf(xk, w.y, acc[4 * q + 1]);
            acc[4 * q + 2] = fmaf(xk, w.z, acc[4 * q + 2]);
            acc[4 * q + 3] = fmaf(xk, w.w, acc[4 * q + 3]);
        }
    }

    float v[35];
#pragma unroll
    for (int j = 0; j < 32; ++j) v[j] = ftanh(acc[j]);

#pragma unroll
    for (int j = 0; j < 32; ++j) acc[j] = bc1[j];
#pragma unroll
    for (int k = 0; k < 32; ++k) {
        float xk = v[k];
        const float4* w4 = (const float4*)(Wc1 + k * 32);
#pragma unroll
        for (int q = 0; q < 8; ++q) {
            float4 w = w4[q];
            acc[4 * q + 0] = fmaf(xk, w.x, acc[4 * q + 0]);
            acc[4 * q + 1] = fmaf(xk, w.y, acc[4 * q + 1]);
            acc[4 * q + 2] = fmaf(xk, w.z, acc[4 * q + 2]);
            acc[4 * q + 3] = fmaf(xk, w.w, acc[4 * q + 3]);
        }
    }
    float cw = 0.0f;
#pragma unroll
    for (int j = 0; j < 32; ++j) cw = fmaf(ftanh(acc[j]), Wc2[j], cw);
    cw = ftanh(cw);

    float s = cw * __builtin_amdgcn_rcpf(__builtin_amdgcn_sqrtf(d2) + 1.0f);
    v[32] = rx * s; v[33] = ry * s; v[34] = rz * s;

    // wave-level segmented inclusive scan; rows contiguous after sort.
#define SEGSTEP(D)                                                \
    {                                                             \
        int rup = __shfl_up(seg, D);                              \
        bool ok = (lane >= D) && (rup == seg);                    \
        _Pragma("unroll")                                         \
        for (int k = 0; k < 35; ++k) {                            \
            float o = __shfl_up(v[k], D);                         \
            v[k] += ok ? o : 0.0f;                                \
        }                                                         \
    }
    SEGSTEP(1) SEGSTEP(2) SEGSTEP(4) SEGSTEP(8) SEGSTEP(16) SEGSTEP(32)
#undef SEGSTEP

    int rdn = __shfl_down(seg, 1);
    bool tail = (lane == 63) || (rdn != seg);
    if (tail && seg >= 0) {
        float* ar = agg + (size_t)seg * 32;
#pragma unroll
        for (int k = 0; k < 32; ++k) atomicAdd(ar + k, v[k]);
        float* nr = num + (size_t)seg * 3;
        atomicAdd(nr + 0, v[32]);
        atomicAdd(nr + 1, v[33]);
        atomicAdd(nr + 2, v[34]);
    }
}

// ---------------- fallback: per-edge atomics (round-1, proven; unchanged) ----------------

__global__ __launch_bounds__(THREADS, 4) void edge_kernel_naive(
    const int* __restrict__ row, const int* __restrict__ col,
    const float* __restrict__ coord, const float* __restrict__ h,
    const float* __restrict__ Wm1, const float* __restrict__ bm1,
    const float* __restrict__ Wm2, const float* __restrict__ bm2,
    const float* __restrict__ Wc1, const float* __restrict__ bc1,
    const float* __restrict__ Wc2,
    float* __restrict__ num, float* __restrict__ agg, int E, int N)
{
    __shared__ float sWm1[33 * 32];
    __shared__ float sWm2[32 * 32];
    __shared__ float sWc1[32 * 32];
    __shared__ float sbm1[32], sbm2[32], sbc1[32], sWc2[32];

    for (int i = threadIdx.x; i < 33 * 32; i += THREADS) sWm1[i] = Wm1[i];
    for (int i = threadIdx.x; i < 32 * 32; i += THREADS) sWm2[i] = Wm2[i];
    for (int i = threadIdx.x; i < 32 * 32; i += THREADS) sWc1[i] = Wc1[i];
    if (threadIdx.x < 32) {
        sbm1[threadIdx.x] = bm1[threadIdx.x];
        sbm2[threadIdx.x] = bm2[threadIdx.x];
        sbc1[threadIdx.x] = bc1[threadIdx.x];
        sWc2[threadIdx.x] = Wc2[threadIdx.x];
    }
    __syncthreads();

    int e = blockIdx.x * THREADS + threadIdx.x;
    if (e >= E) return;

    int r = clampi(row[e], 0, N - 1);
    int c = clampi(col[e], 0, N - 1);

    float rx = coord[(size_t)r * 3 + 0] - coord[(size_t)c * 3 + 0];
    float ry = coord[(size_t)r * 3 + 1] - coord[(size_t)c * 3 + 1];
    float rz = coord[(size_t)r * 3 + 2] - coord[(size_t)c * 3 + 2];
    float d2 = rx * rx + ry * ry + rz * rz;

    float x[33];
    {
        const float4* hr = (const float4*)(h + (size_t)r * 16);
        const float4* hc = (const float4*)(h + (size_t)c * 16);
#pragma unroll
        for (int q = 0; q < 4; ++q) {
            float4 a = hr[q];
            x[4 * q + 0] = a.x; x[4 * q + 1] = a.y;
            x[4 * q + 2] = a.z; x[4 * q + 3] = a.w;
        }
#pragma unroll
        for (int q = 0; q < 4; ++q) {
            float4 b = hc[q];
            x[16 + 4 * q + 0] = b.x; x[16 + 4 * q + 1] = b.y;
            x[16 + 4 * q + 2] = b.z; x[16 + 4 * q + 3] = b.w;
        }
        x[32] = d2;
    }

    float acc[32];
#pragma unroll
    for (int j = 0; j < 32; ++j) acc[j] = sbm1[j];
#pragma unroll
    for (int k = 0; k < 33; ++k) {
        float xk = x[k];
        const float4* w4 = (const float4*)(sWm1 + k * 32);
#pragma unroll
        for (int q = 0; q < 8; ++q) {
            float4 w = w4[q];
            acc[4 * q + 0] = fmaf(xk, w.x, acc[4 * q + 0]);
            acc[4 * q + 1] = fmaf(xk, w.y, acc[4 * q + 1]);
            acc[4 * q + 2] = fmaf(xk, w.z, acc[4 * q + 2]);
            acc[4 * q + 3] = fmaf(xk, w.w, acc[4 * q + 3]);
        }
    }
    float t1[32];
#pragma unroll
    for (int j = 0; j < 32; ++j) t1[j] = ftanh(acc[j]);

#pragma unroll
    for (int j = 0; j < 32; ++j) acc[j] = sbm2[j];
#pragma unroll
    for (int k = 0; k < 32; ++k) {
        float xk = t1[k];
        const float4* w4 = (const float4*)(sWm2 + k * 32);
#pragma unroll
        for (int q = 0; q < 8; ++q) {
            float4 w = w4[q];
            acc[4 * q + 0] = fmaf(xk, w.x, acc[4 * q + 0]);
            acc[4 * q + 1] = fmaf(xk, w.y, acc[4 * q + 1]);
            acc[4 * q + 2] = fmaf(xk, w.z, acc[4 * q + 2]);
            acc[4 * q + 3] = fmaf(xk, w.w, acc[4 * q + 3]);
        }
    }
    float m[32];
#pragma unroll
    for (int j = 0; j < 32; ++j) m[j] = ftanh(acc[j]);

#pragma unroll
    for (int j = 0; j < 32; ++j) acc[j] = sbc1[j];
#pragma unroll
    for (int k = 0; k < 32; ++k) {
        float xk = m[k];
        const float4* w4 = (const float4*)(sWc1 + k * 32);
#pragma unroll
        for (int q = 0; q < 8; ++q) {
            float4 w = w4[q];
            acc[4 * q + 0] = fmaf(xk, w.x, acc[4 * q + 0]);
            acc[4 * q + 1] = fmaf(xk, w.y, acc[4 * q + 1]);
            acc[4 * q + 2] = fmaf(xk, w.z, acc[4 * q + 2]);
            acc[4 * q + 3] = fmaf(xk, w.w, acc[4 * q + 3]);
        }
    }
    float cw = 0.0f;
#pragma unroll
    for (int j = 0; j < 32; ++j) cw = fmaf(ftanh(acc[j]), sWc2[j], cw);
    cw = ftanh(cw);

    float s = cw * __builtin_amdgcn_rcpf(__builtin_amdgcn_sqrtf(d2) + 1.0f);

    float* nr = num + (size_t)r * 3;
    atomicAdd(nr + 0, rx * s);
    atomicAdd(nr + 1, ry * s);
    atomicAdd(nr + 2, rz * s);
    float* ar = agg + (size_t)r * 32;
#pragma unroll
    for (int k = 0; k < 32; ++k) atomicAdd(ar + k, m[k]);
}

// ---------------- node update (unchanged from round 9/10) ----------------

__global__ __launch_bounds__(THREADS, 4) void node_kernel(
    const float* __restrict__ coord_in, const float* __restrict__ h_in,
    const float* __restrict__ num, const float* __restrict__ agg,
    const int* __restrict__ cnt, const float* __restrict__ mask,
    const float* __restrict__ Wn1, const float* __restrict__ bn1,
    const float* __restrict__ Wn2, const float* __restrict__ bn2,
    float* __restrict__ coord_out, float* __restrict__ h_out, int N)
{
    __shared__ float sWn1[48 * 32];
    __shared__ float sWn2[32 * 16];
    __shared__ float sbn1[32], sbn2[16];

    for (int i = threadIdx.x; i < 48 * 32; i += THREADS) sWn1[i] = Wn1[i];
    for (int i = threadIdx.x; i < 32 * 16; i += THREADS) sWn2[i] = Wn2[i];
    if (threadIdx.x < 32) sbn1[threadIdx.x] = bn1[threadIdx.x];
    if (threadIdx.x < 16) sbn2[threadIdx.x] = bn2[threadIdx.x];
    __syncthreads();

    int i = blockIdx.x * THREADS + threadIdx.x;
    if (i >= N) return;

    float msk = mask[i];
    float inv_cnt = __builtin_amdgcn_rcpf(fmaxf((float)cnt[i], 1.0f));

#pragma unroll
    for (int dd = 0; dd < 3; ++dd) {
        float cv = coord_in[(size_t)i * 3 + dd];
        float ov = cv + num[(size_t)i * 3 + dd] * inv_cnt;
        coord_out[(size_t)i * 3 + dd] = ov * msk + cv * (1.0f - msk);
    }

    float hv[16];
    float x[48];
    {
        const float4* hp = (const float4*)(h_in + (size_t)i * 16);
#pragma unroll
        for (int q = 0; q < 4; ++q) {
            float4 a = hp[q];
            hv[4 * q + 0] = a.x; hv[4 * q + 1] = a.y;
            hv[4 * q + 2] = a.z; hv[4 * q + 3] = a.w;
            x[4 * q + 0] = a.x; x[4 * q + 1] = a.y;
            x[4 * q + 2] = a.z; x[4 * q + 3] = a.w;
        }
        const float4* ap = (const float4*)(agg + (size_t)i * 32);
#pragma unroll
        for (int q = 0; q < 8; ++q) {
            float4 a = ap[q];
            x[16 + 4 * q + 0] = a.x; x[16 + 4 * q + 1] = a.y;
            x[16 + 4 * q + 2] = a.z; x[16 + 4 * q + 3] = a.w;
        }
    }

    float acc[32];
#pragma unroll
    for (int j = 0; j < 32; ++j) acc[j] = sbn1[j];
#pragma unroll
    for (int k = 0; k < 48; ++k) {
        float xk = x[k];
        const float4* w4 = (const float4*)(sWn1 + k * 32);
#pragma unroll
        for (int q = 0; q < 8; ++q) {
            float4 w = w4[q];
            acc[4 * q + 0] = fmaf(xk, w.x, acc[4 * q + 0]);
            acc[4 * q + 1] = fmaf(xk, w.y, acc[4 * q + 1]);
            acc[4 * q + 2] = fmaf(xk, w.z, acc[4 * q + 2]);
            acc[4 * q + 3] = fmaf(xk, w.w, acc[4 * q + 3]);
        }
    }
    float t[32];
#pragma unroll
    for (int j = 0; j < 32; ++j) t[j] = ftanh(acc[j]);

    float acc2[16];
#pragma unroll
    for (int j = 0; j < 16; ++j) acc2[j] = sbn2[j];
#pragma unroll
    for (int k = 0; k < 32; ++k) {
        float xk = t[k];
        const float4* w4 = (const float4*)(sWn2 + k * 16);
#pragma unroll
        for (int q = 0; q < 4; ++q) {
            float4 w = w4[q];
            acc2[4 * q + 0] = fmaf(xk, w.x, acc2[4 * q + 0]);
            acc2[4 * q + 1] = fmaf(xk, w.y, acc2[4 * q + 1]);
            acc2[4 * q + 2] = fmaf(xk, w.z, acc2[4 * q + 2]);
            acc2[4 * q + 3] = fmaf(xk, w.w, acc2[4 * q + 3]);
        }
    }

    float hn[16];
    float mean = 0.0f;
#pragma unroll
    for (int j = 0; j < 16; ++j) { hn[j] = hv[j] + acc2[j]; mean += hn[j]; }
    mean *= (1.0f / 16.0f);
    float var = 0.0f;
#pragma unroll
    for (int j = 0; j < 16; ++j) { float d = hn[j] - mean; var = fmaf(d, d, var); }
    var *= (1.0f / 16.0f);
    float stdv = __builtin_amdgcn_sqrtf(var + 1e-5f);
    float sc = __builtin_amdgcn_rsqf(stdv);   // (var+eps)^(-1/4)

#pragma unroll
    for (int j = 0; j < 16; ++j) {
        h_out[(size_t)i * 16 + j] = hn[j] * sc * msk + hv[j] * (1.0f - msk);
    }
}

extern "C" void kernel_launch(void* const* d_in, const int* in_sizes, int n_in,
                              void* d_out, int out_size, void* d_ws, size_t ws_size,
                              hipStream_t stream) {
    const int*   edge_index = (const int*)d_in[0];
    const float* coord      = (const float*)d_in[1];
    const float* h          = (const float*)d_in[2];
    const float* fire       = (const float*)d_in[3];
    const float* Wm1 = (const float*)d_in[4];
    const float* bm1 = (const float*)d_in[5];
    const float* Wm2 = (const float*)d_in[6];
    const float* bm2 = (const float*)d_in[7];
    const float* Wc1 = (const float*)d_in[8];
    const float* bc1 = (const float*)d_in[9];
    const float* Wc2 = (const float*)d_in[10];
    const float* Wn1 = (const float*)d_in[11];
    const float* bn1 = (const float*)d_in[12];
    const float* Wn2 = (const float*)d_in[13];
    const float* bn2 = (const float*)d_in[14];

    const int E = in_sizes[0] / 2;
    const int N = in_sizes[1] / 3;
    const int* row = edge_index;
    const int* col = edge_index + E;

    // ws layout: num 3N f32 | agg 32N f32 | cnth N i32 | startA N i32 | rc E i32
    float* ws     = (float*)d_ws;
    float* num    = ws;
    float* agg    = ws + (size_t)N * 3;
    int*   cnth   = (int*)(ws + (size_t)N * 35);
    int*   startA = cnth + N;
    int*   rc     = startA + N;

    float* out_coord = (float*)d_out;
    float* out_h     = (float*)d_out + (size_t)N * 3;

    const int eb = (E + THREADS - 1) / THREADS;
    const int nb = (N + THREADS - 1) / THREADS;

    const size_t need_sorted = ((size_t)N * 37 + (size_t)E) * sizeof(float) + (1u << 20);

    if (ws_size >= need_sorted && N <= 65535) {
        // ---- one-time CSR build with packed (row<<16|col) stream ----
        hipMemsetAsync(d_ws, 0, (size_t)N * 36 * sizeof(float), stream);
        hist_kernel<<<eb, THREADS, 0, stream>>>(row, cnth, E, N);
        scan_kernel<<<1, THREADS, 0, stream>>>(cnth, startA, N);
        scatter_rc_kernel<<<eb, THREADS, 0, stream>>>(row, col, startA, rc, E, N);

        edge_kernel_sorted<<<eb, THREADS, 0, stream>>>(rc, coord, h,
            Wm1, bm1, Wm2, bm2, Wc1, bc1, Wc2, num, agg, E, N);
        node_kernel<<<nb, THREADS, 0, stream>>>(coord, h, num, agg, cnth, fire,
            Wn1, bn1, Wn2, bn2, out_coord, out_h, N);

        hipMemsetAsync(num, 0, (size_t)N * 35 * sizeof(float), stream);
        edge_kernel_sorted<<<eb, THREADS, 0, stream>>>(rc, out_coord, out_h,
            Wm1, bm1, Wm2, bm2, Wc1, bc1, Wc2, num, agg, E, N);
        node_kernel<<<nb, THREADS, 0, stream>>>(out_coord, out_h, num, agg, cnth, fire + N,
            Wn1, bn1, Wn2, bn2, out_coord, out_h, N);
    } else {
        // ---- fallback: proven round-1 atomic path (7.2 MB) ----
        hipMemsetAsync(d_ws, 0, (size_t)N * 36 * sizeof(float), stream);
        hist_kernel<<<eb, THREADS, 0, stream>>>(row, cnth, E, N);

        edge_kernel_naive<<<eb, THREADS, 0, stream>>>(row, col, coord, h,
            Wm1, bm1, Wm2, bm2, Wc1, bc1, Wc2, num, agg, E, N);
        node_kernel<<<nb, THREADS, 0, stream>>>(coord, h, num, agg, cnth, fire,
            Wn1, bn1, Wn2, bn2, out_coord, out_h, N);

        hipMemsetAsync(num, 0, (size_t)N * 35 * sizeof(float), stream);
        edge_kernel_naive<<<eb, THREADS, 0, stream>>>(row, col, out_coord, out_h,
            Wm1, bm1, Wm2, bm2, Wc1, bc1, Wc2, num, agg, E, N);
        node_kernel<<<nb, THREADS, 0, stream>>>(out_coord, out_h, num, agg, cnth, fire + N,
            Wn1, bn1, Wn2, bn2, out_coord, out_h, N);
    }
}

// Round 19
// 660.365 us; speedup vs baseline: 1.4590x; 1.1150x over previous
//
#include <hip/hip_runtime.h>

#define THREADS 256

// clamp-free fast tanh: 1 - 2/(e^2x + 1).
__device__ __forceinline__ float ftanh(float x) {
    float t = __expf(2.0f * x);
    return fmaf(-2.0f, __builtin_amdgcn_rcpf(t + 1.0f), 1.0f);
}

__device__ __forceinline__ int clampi(int v, int lo, int hi) {
    return v < lo ? lo : (v > hi ? hi : v);
}

// ---------------- CSR build: histogram -> 2-level coalesced scan -> scatter(packed rc) ----------------

__global__ __launch_bounds__(THREADS) void hist_kernel(
    const int* __restrict__ row, int* __restrict__ cnt, int E, int N)
{
    int e = blockIdx.x * THREADS + threadIdx.x;
    if (e < E) {
        int r = row[e];
        if ((unsigned)r < (unsigned)N) atomicAdd(&cnt[r], 1);
    }
}

// level 1: per-block coalesced exclusive scan; block totals to bsum
__global__ __launch_bounds__(THREADS) void scan_blocks(
    const int* __restrict__ cnt, int* __restrict__ start,
    int* __restrict__ bsum, int N)
{
    __shared__ int ssum[THREADS];
    int t = threadIdx.x;
    int i = blockIdx.x * THREADS + t;
    int v = (i < N) ? cnt[i] : 0;
    ssum[t] = v;
    __syncthreads();
    for (int d = 1; d < THREADS; d <<= 1) {
        int u = (t >= d) ? ssum[t - d] : 0;
        __syncthreads();
        ssum[t] += u;
        __syncthreads();
    }
    if (i < N) start[i] = ssum[t] - v;      // block-local exclusive
    if (t == THREADS - 1) bsum[blockIdx.x] = ssum[t];
}

// level 2: exclusive scan of block sums (nb <= 256 guaranteed by N <= 65535)
__global__ __launch_bounds__(THREADS) void scan_bsums(
    int* __restrict__ bsum, int nb)
{
    __shared__ int ssum[THREADS];
    int t = threadIdx.x;
    int v = (t < nb) ? bsum[t] : 0;
    ssum[t] = v;
    __syncthreads();
    for (int d = 1; d < THREADS; d <<= 1) {
        int u = (t >= d) ? ssum[t - d] : 0;
        __syncthreads();
        ssum[t] += u;
        __syncthreads();
    }
    if (t < nb) bsum[t] = ssum[t] - v;      // exclusive block offsets
}

// level 3: add block offsets
__global__ __launch_bounds__(THREADS) void scan_add(
    int* __restrict__ start, const int* __restrict__ bsum, int N)
{
    int i = blockIdx.x * THREADS + threadIdx.x;
    if (i < N) start[i] += bsum[blockIdx.x];
}

// bump start[] in place; rc[pos] = (row<<16)|col packed (requires N <= 65535).
__global__ __launch_bounds__(THREADS) void scatter_rc_kernel(
    const int* __restrict__ row, const int* __restrict__ col,
    int* __restrict__ start, int* __restrict__ rc, int E, int N)
{
    int e = blockIdx.x * THREADS + threadIdx.x;
    if (e < E) {
        int r = row[e];
        if ((unsigned)r < (unsigned)N) {
            int pos = atomicAdd(&start[r], 1);
            if ((unsigned)pos < (unsigned)E) {
                int c = clampi(col[e], 0, N - 1);
                rc[pos] = (int)(((unsigned)r << 16) | (unsigned)c);
            }
        }
    }
}

// ---------------- edge MLP (sorted, packed rc stream) + wave-segmented reduce ----------------
// Round-11 proven body: weights read directly from global with wave-uniform
// indices -> hipcc scalarizes to s_load (scalar pipe) + v_fmac with SGPR
// weight operand. No LDS in this kernel.

__global__ __launch_bounds__(THREADS, 4) void edge_kernel_sorted(
    const int* __restrict__ rc,
    const float* __restrict__ coord, const float* __restrict__ h,
    const float* __restrict__ Wm1, const float* __restrict__ bm1,
    const float* __restrict__ Wm2, const float* __restrict__ bm2,
    const float* __restrict__ Wc1, const float* __restrict__ bc1,
    const float* __restrict__ Wc2,
    float* __restrict__ num, float* __restrict__ agg, int E, int N)
{
    int e = blockIdx.x * THREADS + threadIdx.x;
    int lane = threadIdx.x & 63;

    int r = 0, c = 0, seg = -1;
    if (e < E) {
        // sequential single-use stream: nontemporal so it doesn't evict h/coord from L2
        unsigned p = (unsigned)__builtin_nontemporal_load(&rc[e]);
        r = clampi((int)(p >> 16), 0, N - 1);
        c = clampi((int)(p & 0xFFFFu), 0, N - 1);
        seg = r;
    }

    float rx = coord[(size_t)r * 3 + 0] - coord[(size_t)c * 3 + 0];
    float ry = coord[(size_t)r * 3 + 1] - coord[(size_t)c * 3 + 1];
    float rz = coord[(size_t)r * 3 + 2] - coord[(size_t)c * 3 + 2];
    float d2 = rx * rx + ry * ry + rz * rz;

    float x[33];
    {
        const float4* hr = (const float4*)(h + (size_t)r * 16);
        const float4* hc = (const float4*)(h + (size_t)c * 16);
#pragma unroll
        for (int q = 0; q < 4; ++q) {
            float4 a = hr[q];
            x[4 * q + 0] = a.x; x[4 * q + 1] = a.y;
            x[4 * q + 2] = a.z; x[4 * q + 3] = a.w;
        }
#pragma unroll
        for (int q = 0; q < 4; ++q) {
            float4 b = hc[q];
            x[16 + 4 * q + 0] = b.x; x[16 + 4 * q + 1] = b.y;
            x[16 + 4 * q + 2] = b.z; x[16 + 4 * q + 3] = b.w;
        }
        x[32] = d2;
    }

    float acc[32];
#pragma unroll
    for (int j = 0; j < 32; ++j) acc[j] = bm1[j];
#pragma unroll
    for (int k = 0; k < 33; ++k) {
        float xk = x[k];
        const float4* w4 = (const float4*)(Wm1 + k * 32);
#pragma unroll
        for (int q = 0; q < 8; ++q) {
            float4 w = w4[q];
            acc[4 * q + 0] = fmaf(xk, w.x, acc[4 * q + 0]);
            acc[4 * q + 1] = fmaf(xk, w.y, acc[4 * q + 1]);
            acc[4 * q + 2] = fmaf(xk, w.z, acc[4 * q + 2]);
            acc[4 * q + 3] = fmaf(xk, w.w, acc[4 * q + 3]);
        }
    }
    float t1[32];
#pragma unroll
    for (int j = 0; j < 32; ++j) t1[j] = ftanh(acc[j]);

#pragma unroll
    for (int j = 0; j < 32; ++j) acc[j] = bm2[j];
#pragma unroll
    for (int k = 0; k < 32; ++k) {
        float xk = t1[k];
        const float4* w4 = (const float4*)(Wm2 + k * 32);
#pragma unroll
        for (int q = 0; q < 8; ++q) {
            float4 w = w4[q];
            acc[4 * q + 0] = fmaf(xk, w.x, acc[4 * q + 0]);
            acc[4 * q + 1] = fmaf(xk, w.y, acc[4 * q + 1]);
            acc[4 * q + 2] = fmaf(xk, w.z, acc[4 * q + 2]);
            acc[4 * q + 3] = fmaf(xk, w.w, acc[4 * q + 3]);
        }
    }

    float v[35];
#pragma unroll
    for (int j = 0; j < 32; ++j) v[j] = ftanh(acc[j]);

#pragma unroll
    for (int j = 0; j < 32; ++j) acc[j] = bc1[j];
#pragma unroll
    for (int k = 0; k < 32; ++k) {
        float xk = v[k];
        const float4* w4 = (const float4*)(Wc1 + k * 32);
#pragma unroll
        for (int q = 0; q < 8; ++q) {
            float4 w = w4[q];
            acc[4 * q + 0] = fmaf(xk, w.x, acc[4 * q + 0]);
            acc[4 * q + 1] = fmaf(xk, w.y, acc[4 * q + 1]);
            acc[4 * q + 2] = fmaf(xk, w.z, acc[4 * q + 2]);
            acc[4 * q + 3] = fmaf(xk, w.w, acc[4 * q + 3]);
        }
    }
    float cw = 0.0f;
#pragma unroll
    for (int j = 0; j < 32; ++j) cw = fmaf(ftanh(acc[j]), Wc2[j], cw);
    cw = ftanh(cw);

    float s = cw * __builtin_amdgcn_rcpf(__builtin_amdgcn_sqrtf(d2) + 1.0f);
    v[32] = rx * s; v[33] = ry * s; v[34] = rz * s;

    // wave-level segmented inclusive scan; rows contiguous after sort.
#define SEGSTEP(D)                                                \
    {                                                             \
        int rup = __shfl_up(seg, D);                              \
        bool ok = (lane >= D) && (rup == seg);                    \
        _Pragma("unroll")                                         \
        for (int k = 0; k < 35; ++k) {                            \
            float o = __shfl_up(v[k], D);                         \
            v[k] += ok ? o : 0.0f;                                \
        }                                                         \
    }
    SEGSTEP(1) SEGSTEP(2) SEGSTEP(4) SEGSTEP(8) SEGSTEP(16) SEGSTEP(32)
#undef SEGSTEP

    int rdn = __shfl_down(seg, 1);
    bool tail = (lane == 63) || (rdn != seg);
    if (tail && seg >= 0) {
        float* ar = agg + (size_t)seg * 32;
#pragma unroll
        for (int k = 0; k < 32; ++k) atomicAdd(ar + k, v[k]);
        float* nr = num + (size_t)seg * 3;
        atomicAdd(nr + 0, v[32]);
        atomicAdd(nr + 1, v[33]);
        atomicAdd(nr + 2, v[34]);
    }
}

// ---------------- fallback: per-edge atomics (round-1, proven; unchanged) ----------------

__global__ __launch_bounds__(THREADS, 4) void edge_kernel_naive(
    const int* __restrict__ row, const int* __restrict__ col,
    const float* __restrict__ coord, const float* __restrict__ h,
    const float* __restrict__ Wm1, const float* __restrict__ bm1,
    const float* __restrict__ Wm2, const float* __restrict__ bm2,
    const float* __restrict__ Wc1, const float* __restrict__ bc1,
    const float* __restrict__ Wc2,
    float* __restrict__ num, float* __restrict__ agg, int E, int N)
{
    __shared__ float sWm1[33 * 32];
    __shared__ float sWm2[32 * 32];
    __shared__ float sWc1[32 * 32];
    __shared__ float sbm1[32], sbm2[32], sbc1[32], sWc2[32];

    for (int i = threadIdx.x; i < 33 * 32; i += THREADS) sWm1[i] = Wm1[i];
    for (int i = threadIdx.x; i < 32 * 32; i += THREADS) sWm2[i] = Wm2[i];
    for (int i = threadIdx.x; i < 32 * 32; i += THREADS) sWc1[i] = Wc1[i];
    if (threadIdx.x < 32) {
        sbm1[threadIdx.x] = bm1[threadIdx.x];
        sbm2[threadIdx.x] = bm2[threadIdx.x];
        sbc1[threadIdx.x] = bc1[threadIdx.x];
        sWc2[threadIdx.x] = Wc2[threadIdx.x];
    }
    __syncthreads();

    int e = blockIdx.x * THREADS + threadIdx.x;
    if (e >= E) return;

    int r = clampi(row[e], 0, N - 1);
    int c = clampi(col[e], 0, N - 1);

    float rx = coord[(size_t)r * 3 + 0] - coord[(size_t)c * 3 + 0];
    float ry = coord[(size_t)r * 3 + 1] - coord[(size_t)c * 3 + 1];
    float rz = coord[(size_t)r * 3 + 2] - coord[(size_t)c * 3 + 2];
    float d2 = rx * rx + ry * ry + rz * rz;

    float x[33];
    {
        const float4* hr = (const float4*)(h + (size_t)r * 16);
        const float4* hc = (const float4*)(h + (size_t)c * 16);
#pragma unroll
        for (int q = 0; q < 4; ++q) {
            float4 a = hr[q];
            x[4 * q + 0] = a.x; x[4 * q + 1] = a.y;
            x[4 * q + 2] = a.z; x[4 * q + 3] = a.w;
        }
#pragma unroll
        for (int q = 0; q < 4; ++q) {
            float4 b = hc[q];
            x[16 + 4 * q + 0] = b.x; x[16 + 4 * q + 1] = b.y;
            x[16 + 4 * q + 2] = b.z; x[16 + 4 * q + 3] = b.w;
        }
        x[32] = d2;
    }

    float acc[32];
#pragma unroll
    for (int j = 0; j < 32; ++j) acc[j] = sbm1[j];
#pragma unroll
    for (int k = 0; k < 33; ++k) {
        float xk = x[k];
        const float4* w4 = (const float4*)(sWm1 + k * 32);
#pragma unroll
        for (int q = 0; q < 8; ++q) {
            float4 w = w4[q];
            acc[4 * q + 0] = fmaf(xk, w.x, acc[4 * q + 0]);
            acc[4 * q + 1] = fmaf(xk, w.y, acc[4 * q + 1]);
            acc[4 * q + 2] = fmaf(xk, w.z, acc[4 * q + 2]);
            acc[4 * q + 3] = fmaf(xk, w.w, acc[4 * q + 3]);
        }
    }
    float t1[32];
#pragma unroll
    for (int j = 0; j < 32; ++j) t1[j] = ftanh(acc[j]);

#pragma unroll
    for (int j = 0; j < 32; ++j) acc[j] = sbm2[j];
#pragma unroll
    for (int k = 0; k < 32; ++k) {
        float xk = t1[k];
        const float4* w4 = (const float4*)(sWm2 + k * 32);
#pragma unroll
        for (int q = 0; q < 8; ++q) {
            float4 w = w4[q];
            acc[4 * q + 0] = fmaf(xk, w.x, acc[4 * q + 0]);
            acc[4 * q + 1] = fmaf(xk, w.y, acc[4 * q + 1]);
            acc[4 * q + 2] = fmaf(xk, w.z, acc[4 * q + 2]);
            acc[4 * q + 3] = fmaf(xk, w.w, acc[4 * q + 3]);
        }
    }
    float m[32];
#pragma unroll
    for (int j = 0; j < 32; ++j) m[j] = ftanh(acc[j]);

#pragma unroll
    for (int j = 0; j < 32; ++j) acc[j] = sbc1[j];
#pragma unroll
    for (int k = 0; k < 32; ++k) {
        float xk = m[k];
        const float4* w4 = (const float4*)(sWc1 + k * 32);
#pragma unroll
        for (int q = 0; q < 8; ++q) {
            float4 w = w4[q];
            acc[4 * q + 0] = fmaf(xk, w.x, acc[4 * q + 0]);
            acc[4 * q + 1] = fmaf(xk, w.y, acc[4 * q + 1]);
            acc[4 * q + 2] = fmaf(xk, w.z, acc[4 * q + 2]);
            acc[4 * q + 3] = fmaf(xk, w.w, acc[4 * q + 3]);
        }
    }
    float cw = 0.0f;
#pragma unroll
    for (int j = 0; j < 32; ++j) cw = fmaf(ftanh(acc[j]), sWc2[j], cw);
    cw = ftanh(cw);

    float s = cw * __builtin_amdgcn_rcpf(__builtin_amdgcn_sqrtf(d2) + 1.0f);

    float* nr = num + (size_t)r * 3;
    atomicAdd(nr + 0, rx * s);
    atomicAdd(nr + 1, ry * s);
    atomicAdd(nr + 2, rz * s);
    float* ar = agg + (size_t)r * 32;
#pragma unroll
    for (int k = 0; k < 32; ++k) atomicAdd(ar + k, m[k]);
}

// ---------------- node update (unchanged) ----------------

__global__ __launch_bounds__(THREADS, 4) void node_kernel(
    const float* __restrict__ coord_in, const float* __restrict__ h_in,
    const float* __restrict__ num, const float* __restrict__ agg,
    const int* __restrict__ cnt, const float* __restrict__ mask,
    const float* __restrict__ Wn1, const float* __restrict__ bn1,
    const float* __restrict__ Wn2, const float* __restrict__ bn2,
    float* __restrict__ coord_out, float* __restrict__ h_out, int N)
{
    __shared__ float sWn1[48 * 32];
    __shared__ float sWn2[32 * 16];
    __shared__ float sbn1[32], sbn2[16];

    for (int i = threadIdx.x; i < 48 * 32; i += THREADS) sWn1[i] = Wn1[i];
    for (int i = threadIdx.x; i < 32 * 16; i += THREADS) sWn2[i] = Wn2[i];
    if (threadIdx.x < 32) sbn1[threadIdx.x] = bn1[threadIdx.x];
    if (threadIdx.x < 16) sbn2[threadIdx.x] = bn2[threadIdx.x];
    __syncthreads();

    int i = blockIdx.x * THREADS + threadIdx.x;
    if (i >= N) return;

    float msk = mask[i];
    float inv_cnt = __builtin_amdgcn_rcpf(fmaxf((float)cnt[i], 1.0f));

#pragma unroll
    for (int dd = 0; dd < 3; ++dd) {
        float cv = coord_in[(size_t)i * 3 + dd];
        float ov = cv + num[(size_t)i * 3 + dd] * inv_cnt;
        coord_out[(size_t)i * 3 + dd] = ov * msk + cv * (1.0f - msk);
    }

    float hv[16];
    float x[48];
    {
        const float4* hp = (const float4*)(h_in + (size_t)i * 16);
#pragma unroll
        for (int q = 0; q < 4; ++q) {
            float4 a = hp[q];
            hv[4 * q + 0] = a.x; hv[4 * q + 1] = a.y;
            hv[4 * q + 2] = a.z; hv[4 * q + 3] = a.w;
            x[4 * q + 0] = a.x; x[4 * q + 1] = a.y;
            x[4 * q + 2] = a.z; x[4 * q + 3] = a.w;
        }
        const float4* ap = (const float4*)(agg + (size_t)i * 32);
#pragma unroll
        for (int q = 0; q < 8; ++q) {
            float4 a = ap[q];
            x[16 + 4 * q + 0] = a.x; x[16 + 4 * q + 1] = a.y;
            x[16 + 4 * q + 2] = a.z; x[16 + 4 * q + 3] = a.w;
        }
    }

    float acc[32];
#pragma unroll
    for (int j = 0; j < 32; ++j) acc[j] = sbn1[j];
#pragma unroll
    for (int k = 0; k < 48; ++k) {
        float xk = x[k];
        const float4* w4 = (const float4*)(sWn1 + k * 32);
#pragma unroll
        for (int q = 0; q < 8; ++q) {
            float4 w = w4[q];
            acc[4 * q + 0] = fmaf(xk, w.x, acc[4 * q + 0]);
            acc[4 * q + 1] = fmaf(xk, w.y, acc[4 * q + 1]);
            acc[4 * q + 2] = fmaf(xk, w.z, acc[4 * q + 2]);
            acc[4 * q + 3] = fmaf(xk, w.w, acc[4 * q + 3]);
        }
    }
    float t[32];
#pragma unroll
    for (int j = 0; j < 32; ++j) t[j] = ftanh(acc[j]);

    float acc2[16];
#pragma unroll
    for (int j = 0; j < 16; ++j) acc2[j] = sbn2[j];
#pragma unroll
    for (int k = 0; k < 32; ++k) {
        float xk = t[k];
        const float4* w4 = (const float4*)(sWn2 + k * 16);
#pragma unroll
        for (int q = 0; q < 4; ++q) {
            float4 w = w4[q];
            acc2[4 * q + 0] = fmaf(xk, w.x, acc2[4 * q + 0]);
            acc2[4 * q + 1] = fmaf(xk, w.y, acc2[4 * q + 1]);
            acc2[4 * q + 2] = fmaf(xk, w.z, acc2[4 * q + 2]);
            acc2[4 * q + 3] = fmaf(xk, w.w, acc2[4 * q + 3]);
        }
    }

    float hn[16];
    float mean = 0.0f;
#pragma unroll
    for (int j = 0; j < 16; ++j) { hn[j] = hv[j] + acc2[j]; mean += hn[j]; }
    mean *= (1.0f / 16.0f);
    float var = 0.0f;
#pragma unroll
    for (int j = 0; j < 16; ++j) { float d = hn[j] - mean; var = fmaf(d, d, var); }
    var *= (1.0f / 16.0f);
    float stdv = __builtin_amdgcn_sqrtf(var + 1e-5f);
    float sc = __builtin_amdgcn_rsqf(stdv);   // (var+eps)^(-1/4)

#pragma unroll
    for (int j = 0; j < 16; ++j) {
        h_out[(size_t)i * 16 + j] = hn[j] * sc * msk + hv[j] * (1.0f - msk);
    }
}

extern "C" void kernel_launch(void* const* d_in, const int* in_sizes, int n_in,
                              void* d_out, int out_size, void* d_ws, size_t ws_size,
                              hipStream_t stream) {
    const int*   edge_index = (const int*)d_in[0];
    const float* coord      = (const float*)d_in[1];
    const float* h          = (const float*)d_in[2];
    const float* fire       = (const float*)d_in[3];
    const float* Wm1 = (const float*)d_in[4];
    const float* bm1 = (const float*)d_in[5];
    const float* Wm2 = (const float*)d_in[6];
    const float* bm2 = (const float*)d_in[7];
    const float* Wc1 = (const float*)d_in[8];
    const float* bc1 = (const float*)d_in[9];
    const float* Wc2 = (const float*)d_in[10];
    const float* Wn1 = (const float*)d_in[11];
    const float* bn1 = (const float*)d_in[12];
    const float* Wn2 = (const float*)d_in[13];
    const float* bn2 = (const float*)d_in[14];

    const int E = in_sizes[0] / 2;
    const int N = in_sizes[1] / 3;
    const int* row = edge_index;
    const int* col = edge_index + E;

    // ws layout: num 3N f32 | agg 32N f32 | cnth N i32 | startA N i32 |
    //            bsum 256 i32 | rc E i32
    float* ws     = (float*)d_ws;
    float* num    = ws;
    float* agg    = ws + (size_t)N * 3;
    int*   cnth   = (int*)(ws + (size_t)N * 35);
    int*   startA = cnth + N;
    int*   bsum   = startA + N;
    int*   rc     = bsum + 256;

    float* out_coord = (float*)d_out;
    float* out_h     = (float*)d_out + (size_t)N * 3;

    const int eb = (E + THREADS - 1) / THREADS;
    const int nb = (N + THREADS - 1) / THREADS;

    const size_t need_sorted =
        ((size_t)N * 37 + 256 + (size_t)E) * sizeof(float) + (1u << 20);

    if (ws_size >= need_sorted && N <= 65535) {
        // ---- one-time CSR build with packed (row<<16|col) stream ----
        (void)hipMemsetAsync(d_ws, 0, (size_t)N * 36 * sizeof(float), stream);
        hist_kernel<<<eb, THREADS, 0, stream>>>(row, cnth, E, N);
        scan_blocks<<<nb, THREADS, 0, stream>>>(cnth, startA, bsum, N);
        scan_bsums<<<1, THREADS, 0, stream>>>(bsum, nb);
        scan_add<<<nb, THREADS, 0, stream>>>(startA, bsum, N);
        scatter_rc_kernel<<<eb, THREADS, 0, stream>>>(row, col, startA, rc, E, N);

        edge_kernel_sorted<<<eb, THREADS, 0, stream>>>(rc, coord, h,
            Wm1, bm1, Wm2, bm2, Wc1, bc1, Wc2, num, agg, E, N);
        node_kernel<<<nb, THREADS, 0, stream>>>(coord, h, num, agg, cnth, fire,
            Wn1, bn1, Wn2, bn2, out_coord, out_h, N);

        (void)hipMemsetAsync(num, 0, (size_t)N * 35 * sizeof(float), stream);
        edge_kernel_sorted<<<eb, THREADS, 0, stream>>>(rc, out_coord, out_h,
            Wm1, bm1, Wm2, bm2, Wc1, bc1, Wc2, num, agg, E, N);
        node_kernel<<<nb, THREADS, 0, stream>>>(out_coord, out_h, num, agg, cnth, fire + N,
            Wn1, bn1, Wn2, bn2, out_coord, out_h, N);
    } else {
        // ---- fallback: proven round-1 atomic path (7.2 MB) ----
        (void)hipMemsetAsync(d_ws, 0, (size_t)N * 36 * sizeof(float), stream);
        hist_kernel<<<eb, THREADS, 0, stream>>>(row, cnth, E, N);

        edge_kernel_naive<<<eb, THREADS, 0, stream>>>(row, col, coord, h,
            Wm1, bm1, Wm2, bm2, Wc1, bc1, Wc2, num, agg, E, N);
        node_kernel<<<nb, THREADS, 0, stream>>>(coord, h, num, agg, cnth, fire,
            Wn1, bn1, Wn2, bn2, out_coord, out_h, N);

        (void)hipMemsetAsync(num, 0, (size_t)N * 35 * sizeof(float), stream);
        edge_kernel_naive<<<eb, THREADS, 0, stream>>>(row, col, out_coord, out_h,
            Wm1, bm1, Wm2, bm2, Wc1, bc1, Wc2, num, agg, E, N);
        node_kernel<<<nb, THREADS, 0, stream>>>(out_coord, out_h, num, agg, cnth, fire + N,
            Wn1, bn1, Wn2, bn2, out_coord, out_h, N);
    }
}

// Round 20
// 633.992 us; speedup vs baseline: 1.5197x; 1.0416x over previous
//
#include <hip/hip_runtime.h>

#define THREADS 256

typedef __attribute__((ext_vector_type(2))) _Float16 f16x2;

// pack two f32 into f16x2 via v_cvt_pkrtz_f16_f32 (bit_cast bridges clang's
// __fp16-vector return type to the _Float16-vector fdot2 expects)
__device__ __forceinline__ f16x2 pkrtz(float a, float b) {
    return __builtin_bit_cast(f16x2, __builtin_amdgcn_cvt_pkrtz(a, b));
}

// clamp-free fast tanh: 1 - 2/(e^2x + 1).
__device__ __forceinline__ float ftanh(float x) {
    float t = __expf(2.0f * x);
    return fmaf(-2.0f, __builtin_amdgcn_rcpf(t + 1.0f), 1.0f);
}

__device__ __forceinline__ int clampi(int v, int lo, int hi) {
    return v < lo ? lo : (v > hi ? hi : v);
}

// ---------------- CSR build: histogram -> 2-level coalesced scan -> scatter(packed rc) ----------------

__global__ __launch_bounds__(THREADS) void hist_kernel(
    const int* __restrict__ row, int* __restrict__ cnt, int E, int N)
{
    int e = blockIdx.x * THREADS + threadIdx.x;
    if (e < E) {
        int r = row[e];
        if ((unsigned)r < (unsigned)N) atomicAdd(&cnt[r], 1);
    }
}

// level 1: per-block coalesced exclusive scan; block totals to bsum
__global__ __launch_bounds__(THREADS) void scan_blocks(
    const int* __restrict__ cnt, int* __restrict__ start,
    int* __restrict__ bsum, int N)
{
    __shared__ int ssum[THREADS];
    int t = threadIdx.x;
    int i = blockIdx.x * THREADS + t;
    int v = (i < N) ? cnt[i] : 0;
    ssum[t] = v;
    __syncthreads();
    for (int d = 1; d < THREADS; d <<= 1) {
        int u = (t >= d) ? ssum[t - d] : 0;
        __syncthreads();
        ssum[t] += u;
        __syncthreads();
    }
    if (i < N) start[i] = ssum[t] - v;      // block-local exclusive
    if (t == THREADS - 1) bsum[blockIdx.x] = ssum[t];
}

// level 2: exclusive scan of block sums (nb <= 256 guaranteed by N <= 65535)
__global__ __launch_bounds__(THREADS) void scan_bsums(
    int* __restrict__ bsum, int nb)
{
    __shared__ int ssum[THREADS];
    int t = threadIdx.x;
    int v = (t < nb) ? bsum[t] : 0;
    ssum[t] = v;
    __syncthreads();
    for (int d = 1; d < THREADS; d <<= 1) {
        int u = (t >= d) ? ssum[t - d] : 0;
        __syncthreads();
        ssum[t] += u;
        __syncthreads();
    }
    if (t < nb) bsum[t] = ssum[t] - v;      // exclusive block offsets
}

// level 3: add block offsets
__global__ __launch_bounds__(THREADS) void scan_add(
    int* __restrict__ start, const int* __restrict__ bsum, int N)
{
    int i = blockIdx.x * THREADS + threadIdx.x;
    if (i < N) start[i] += bsum[blockIdx.x];
}

// bump start[] in place; rc[pos] = (row<<16)|col packed (requires N <= 65535).
__global__ __launch_bounds__(THREADS) void scatter_rc_kernel(
    const int* __restrict__ row, const int* __restrict__ col,
    int* __restrict__ start, int* __restrict__ rc, int E, int N)
{
    int e = blockIdx.x * THREADS + threadIdx.x;
    if (e < E) {
        int r = row[e];
        if ((unsigned)r < (unsigned)N) {
            int pos = atomicAdd(&start[r], 1);
            if ((unsigned)pos < (unsigned)E) {
                int c = clampi(col[e], 0, N - 1);
                rc[pos] = (int)(((unsigned)r << 16) | (unsigned)c);
            }
        }
    }
}

// ---------------- one-time f16x2 weight packing (pairs along K) ----------------
// wp[0,544): Wm1 (17 K-pairs x 32, K=33 zero-padded to 34)
// wp[544,1056): Wm2 (16 x 32) ; wp[1056,1568): Wc1 (16 x 32)

__global__ __launch_bounds__(THREADS) void pack_weights(
    const float* __restrict__ Wm1, const float* __restrict__ Wm2,
    const float* __restrict__ Wc1, unsigned* __restrict__ wp)
{
    int i = blockIdx.x * THREADS + threadIdx.x;
    if (i >= 1568) return;
    float a, b;
    if (i < 544) {
        int p = i >> 5, j = i & 31;
        a = (2 * p < 33) ? Wm1[(2 * p) * 32 + j] : 0.0f;
        b = (2 * p + 1 < 33) ? Wm1[(2 * p + 1) * 32 + j] : 0.0f;
    } else if (i < 1056) {
        int k = i - 544;
        int p = k >> 5, j = k & 31;
        a = Wm2[(2 * p) * 32 + j];
        b = Wm2[(2 * p + 1) * 32 + j];
    } else {
        int k = i - 1056;
        int p = k >> 5, j = k & 31;
        a = Wc1[(2 * p) * 32 + j];
        b = Wc1[(2 * p + 1) * 32 + j];
    }
    wp[i] = __builtin_bit_cast(unsigned, pkrtz(a, b));
}

// ---------------- edge MLP (dot2-f16 weights, SMEM-scalarized) + wave-segmented reduce ----------------
// Weights read with wave-uniform indices -> s_load (scalar pipe); v_dot2_f32_f16
// does 2 MACs/instr with f32 accumulate, halving matmul VALU issue vs v_fmac.

__global__ __launch_bounds__(THREADS, 4) void edge_kernel_sorted(
    const int* __restrict__ rc,
    const float* __restrict__ coord, const float* __restrict__ h,
    const unsigned* __restrict__ wp,
    const float* __restrict__ bm1, const float* __restrict__ bm2,
    const float* __restrict__ bc1, const float* __restrict__ Wc2,
    float* __restrict__ num, float* __restrict__ agg, int E, int N)
{
    int e = blockIdx.x * THREADS + threadIdx.x;
    int lane = threadIdx.x & 63;

    int r = 0, c = 0, seg = -1;
    if (e < E) {
        unsigned p = (unsigned)__builtin_nontemporal_load(&rc[e]);
        r = clampi((int)(p >> 16), 0, N - 1);
        c = clampi((int)(p & 0xFFFFu), 0, N - 1);
        seg = r;
    }

    float rx = coord[(size_t)r * 3 + 0] - coord[(size_t)c * 3 + 0];
    float ry = coord[(size_t)r * 3 + 1] - coord[(size_t)c * 3 + 1];
    float rz = coord[(size_t)r * 3 + 2] - coord[(size_t)c * 3 + 2];
    float d2 = rx * rx + ry * ry + rz * rz;

    float x[33];
    {
        const float4* hr = (const float4*)(h + (size_t)r * 16);
        const float4* hc = (const float4*)(h + (size_t)c * 16);
#pragma unroll
        for (int q = 0; q < 4; ++q) {
            float4 a = hr[q];
            x[4 * q + 0] = a.x; x[4 * q + 1] = a.y;
            x[4 * q + 2] = a.z; x[4 * q + 3] = a.w;
        }
#pragma unroll
        for (int q = 0; q < 4; ++q) {
            float4 b = hc[q];
            x[16 + 4 * q + 0] = b.x; x[16 + 4 * q + 1] = b.y;
            x[16 + 4 * q + 2] = b.z; x[16 + 4 * q + 3] = b.w;
        }
        x[32] = d2;
    }

    const unsigned* wp1 = wp;
    const unsigned* wp2 = wp + 544;
    const unsigned* wp3 = wp + 1056;

    // pack inputs as f16 pairs (f32 accumulate keeps precision)
    f16x2 px[17];
#pragma unroll
    for (int p = 0; p < 16; ++p) px[p] = pkrtz(x[2 * p], x[2 * p + 1]);
    px[16] = pkrtz(x[32], 0.0f);

    float acc[32];
#pragma unroll
    for (int j = 0; j < 32; ++j) acc[j] = bm1[j];
#pragma unroll
    for (int p = 0; p < 17; ++p) {
#pragma unroll
        for (int j = 0; j < 32; ++j) {
            f16x2 w = __builtin_bit_cast(f16x2, wp1[p * 32 + j]);
            acc[j] = __builtin_amdgcn_fdot2(px[p], w, acc[j], false);
        }
    }

    f16x2 pt[16];
#pragma unroll
    for (int p = 0; p < 16; ++p)
        pt[p] = pkrtz(ftanh(acc[2 * p]), ftanh(acc[2 * p + 1]));

#pragma unroll
    for (int j = 0; j < 32; ++j) acc[j] = bm2[j];
#pragma unroll
    for (int p = 0; p < 16; ++p) {
#pragma unroll
        for (int j = 0; j < 32; ++j) {
            f16x2 w = __builtin_bit_cast(f16x2, wp2[p * 32 + j]);
            acc[j] = __builtin_amdgcn_fdot2(pt[p], w, acc[j], false);
        }
    }

    // v[0..31] = m, v[32..34] = trans
    float v[35];
#pragma unroll
    for (int j = 0; j < 32; ++j) v[j] = ftanh(acc[j]);

    f16x2 pm[16];
#pragma unroll
    for (int p = 0; p < 16; ++p)
        pm[p] = pkrtz(v[2 * p], v[2 * p + 1]);

#pragma unroll
    for (int j = 0; j < 32; ++j) acc[j] = bc1[j];
#pragma unroll
    for (int p = 0; p < 16; ++p) {
#pragma unroll
        for (int j = 0; j < 32; ++j) {
            f16x2 w = __builtin_bit_cast(f16x2, wp3[p * 32 + j]);
            acc[j] = __builtin_amdgcn_fdot2(pm[p], w, acc[j], false);
        }
    }
    float cw = 0.0f;
#pragma unroll
    for (int j = 0; j < 32; ++j) cw = fmaf(ftanh(acc[j]), Wc2[j], cw);
    cw = ftanh(cw);

    float s = cw * __builtin_amdgcn_rcpf(__builtin_amdgcn_sqrtf(d2) + 1.0f);
    v[32] = rx * s; v[33] = ry * s; v[34] = rz * s;

    // wave-level segmented inclusive scan; rows contiguous after sort.
#define SEGSTEP(D)                                                \
    {                                                             \
        int rup = __shfl_up(seg, D);                              \
        bool ok = (lane >= D) && (rup == seg);                    \
        _Pragma("unroll")                                         \
        for (int k = 0; k < 35; ++k) {                            \
            float o = __shfl_up(v[k], D);                         \
            v[k] += ok ? o : 0.0f;                                \
        }                                                         \
    }
    SEGSTEP(1) SEGSTEP(2) SEGSTEP(4) SEGSTEP(8) SEGSTEP(16) SEGSTEP(32)
#undef SEGSTEP

    int rdn = __shfl_down(seg, 1);
    bool tail = (lane == 63) || (rdn != seg);
    if (tail && seg >= 0) {
        float* ar = agg + (size_t)seg * 32;
#pragma unroll
        for (int k = 0; k < 32; ++k) atomicAdd(ar + k, v[k]);
        float* nr = num + (size_t)seg * 3;
        atomicAdd(nr + 0, v[32]);
        atomicAdd(nr + 1, v[33]);
        atomicAdd(nr + 2, v[34]);
    }
}

// ---------------- fallback: per-edge atomics, f32 LDS weights (round-1, proven) ----------------

__global__ __launch_bounds__(THREADS, 4) void edge_kernel_naive(
    const int* __restrict__ row, const int* __restrict__ col,
    const float* __restrict__ coord, const float* __restrict__ h,
    const float* __restrict__ Wm1, const float* __restrict__ bm1,
    const float* __restrict__ Wm2, const float* __restrict__ bm2,
    const float* __restrict__ Wc1, const float* __restrict__ bc1,
    const float* __restrict__ Wc2,
    float* __restrict__ num, float* __restrict__ agg, int E, int N)
{
    __shared__ float sWm1[33 * 32];
    __shared__ float sWm2[32 * 32];
    __shared__ float sWc1[32 * 32];
    __shared__ float sbm1[32], sbm2[32], sbc1[32], sWc2[32];

    for (int i = threadIdx.x; i < 33 * 32; i += THREADS) sWm1[i] = Wm1[i];
    for (int i = threadIdx.x; i < 32 * 32; i += THREADS) sWm2[i] = Wm2[i];
    for (int i = threadIdx.x; i < 32 * 32; i += THREADS) sWc1[i] = Wc1[i];
    if (threadIdx.x < 32) {
        sbm1[threadIdx.x] = bm1[threadIdx.x];
        sbm2[threadIdx.x] = bm2[threadIdx.x];
        sbc1[threadIdx.x] = bc1[threadIdx.x];
        sWc2[threadIdx.x] = Wc2[threadIdx.x];
    }
    __syncthreads();

    int e = blockIdx.x * THREADS + threadIdx.x;
    if (e >= E) return;

    int r = clampi(row[e], 0, N - 1);
    int c = clampi(col[e], 0, N - 1);

    float rx = coord[(size_t)r * 3 + 0] - coord[(size_t)c * 3 + 0];
    float ry = coord[(size_t)r * 3 + 1] - coord[(size_t)c * 3 + 1];
    float rz = coord[(size_t)r * 3 + 2] - coord[(size_t)c * 3 + 2];
    float d2 = rx * rx + ry * ry + rz * rz;

    float x[33];
    {
        const float4* hr = (const float4*)(h + (size_t)r * 16);
        const float4* hc = (const float4*)(h + (size_t)c * 16);
#pragma unroll
        for (int q = 0; q < 4; ++q) {
            float4 a = hr[q];
            x[4 * q + 0] = a.x; x[4 * q + 1] = a.y;
            x[4 * q + 2] = a.z; x[4 * q + 3] = a.w;
        }
#pragma unroll
        for (int q = 0; q < 4; ++q) {
            float4 b = hc[q];
            x[16 + 4 * q + 0] = b.x; x[16 + 4 * q + 1] = b.y;
            x[16 + 4 * q + 2] = b.z; x[16 + 4 * q + 3] = b.w;
        }
        x[32] = d2;
    }

    float acc[32];
#pragma unroll
    for (int j = 0; j < 32; ++j) acc[j] = sbm1[j];
#pragma unroll
    for (int k = 0; k < 33; ++k) {
        float xk = x[k];
        const float4* w4 = (const float4*)(sWm1 + k * 32);
#pragma unroll
        for (int q = 0; q < 8; ++q) {
            float4 w = w4[q];
            acc[4 * q + 0] = fmaf(xk, w.x, acc[4 * q + 0]);
            acc[4 * q + 1] = fmaf(xk, w.y, acc[4 * q + 1]);
            acc[4 * q + 2] = fmaf(xk, w.z, acc[4 * q + 2]);
            acc[4 * q + 3] = fmaf(xk, w.w, acc[4 * q + 3]);
        }
    }
    float t1[32];
#pragma unroll
    for (int j = 0; j < 32; ++j) t1[j] = ftanh(acc[j]);

#pragma unroll
    for (int j = 0; j < 32; ++j) acc[j] = sbm2[j];
#pragma unroll
    for (int k = 0; k < 32; ++k) {
        float xk = t1[k];
        const float4* w4 = (const float4*)(sWm2 + k * 32);
#pragma unroll
        for (int q = 0; q < 8; ++q) {
            float4 w = w4[q];
            acc[4 * q + 0] = fmaf(xk, w.x, acc[4 * q + 0]);
            acc[4 * q + 1] = fmaf(xk, w.y, acc[4 * q + 1]);
            acc[4 * q + 2] = fmaf(xk, w.z, acc[4 * q + 2]);
            acc[4 * q + 3] = fmaf(xk, w.w, acc[4 * q + 3]);
        }
    }
    float m[32];
#pragma unroll
    for (int j = 0; j < 32; ++j) m[j] = ftanh(acc[j]);

#pragma unroll
    for (int j = 0; j < 32; ++j) acc[j] = sbc1[j];
#pragma unroll
    for (int k = 0; k < 32; ++k) {
        float xk = m[k];
        const float4* w4 = (const float4*)(sWc1 + k * 32);
#pragma unroll
        for (int q = 0; q < 8; ++q) {
            float4 w = w4[q];
            acc[4 * q + 0] = fmaf(xk, w.x, acc[4 * q + 0]);
            acc[4 * q + 1] = fmaf(xk, w.y, acc[4 * q + 1]);
            acc[4 * q + 2] = fmaf(xk, w.z, acc[4 * q + 2]);
            acc[4 * q + 3] = fmaf(xk, w.w, acc[4 * q + 3]);
        }
    }
    float cw = 0.0f;
#pragma unroll
    for (int j = 0; j < 32; ++j) cw = fmaf(ftanh(acc[j]), sWc2[j], cw);
    cw = ftanh(cw);

    float s = cw * __builtin_amdgcn_rcpf(__builtin_amdgcn_sqrtf(d2) + 1.0f);

    float* nr = num + (size_t)r * 3;
    atomicAdd(nr + 0, rx * s);
    atomicAdd(nr + 1, ry * s);
    atomicAdd(nr + 2, rz * s);
    float* ar = agg + (size_t)r * 32;
#pragma unroll
    for (int k = 0; k < 32; ++k) atomicAdd(ar + k, m[k]);
}

// ---------------- node update (unchanged) ----------------

__global__ __launch_bounds__(THREADS, 4) void node_kernel(
    const float* __restrict__ coord_in, const float* __restrict__ h_in,
    const float* __restrict__ num, const float* __restrict__ agg,
    const int* __restrict__ cnt, const float* __restrict__ mask,
    const float* __restrict__ Wn1, const float* __restrict__ bn1,
    const float* __restrict__ Wn2, const float* __restrict__ bn2,
    float* __restrict__ coord_out, float* __restrict__ h_out, int N)
{
    __shared__ float sWn1[48 * 32];
    __shared__ float sWn2[32 * 16];
    __shared__ float sbn1[32], sbn2[16];

    for (int i = threadIdx.x; i < 48 * 32; i += THREADS) sWn1[i] = Wn1[i];
    for (int i = threadIdx.x; i < 32 * 16; i += THREADS) sWn2[i] = Wn2[i];
    if (threadIdx.x < 32) sbn1[threadIdx.x] = bn1[threadIdx.x];
    if (threadIdx.x < 16) sbn2[threadIdx.x] = bn2[threadIdx.x];
    __syncthreads();

    int i = blockIdx.x * THREADS + threadIdx.x;
    if (i >= N) return;

    float msk = mask[i];
    float inv_cnt = __builtin_amdgcn_rcpf(fmaxf((float)cnt[i], 1.0f));

#pragma unroll
    for (int dd = 0; dd < 3; ++dd) {
        float cv = coord_in[(size_t)i * 3 + dd];
        float ov = cv + num[(size_t)i * 3 + dd] * inv_cnt;
        coord_out[(size_t)i * 3 + dd] = ov * msk + cv * (1.0f - msk);
    }

    float hv[16];
    float x[48];
    {
        const float4* hp = (const float4*)(h_in + (size_t)i * 16);
#pragma unroll
        for (int q = 0; q < 4; ++q) {
            float4 a = hp[q];
            hv[4 * q + 0] = a.x; hv[4 * q + 1] = a.y;
            hv[4 * q + 2] = a.z; hv[4 * q + 3] = a.w;
            x[4 * q + 0] = a.x; x[4 * q + 1] = a.y;
            x[4 * q + 2] = a.z; x[4 * q + 3] = a.w;
        }
        const float4* ap = (const float4*)(agg + (size_t)i * 32);
#pragma unroll
        for (int q = 0; q < 8; ++q) {
            float4 a = ap[q];
            x[16 + 4 * q + 0] = a.x; x[16 + 4 * q + 1] = a.y;
            x[16 + 4 * q + 2] = a.z; x[16 + 4 * q + 3] = a.w;
        }
    }

    float acc[32];
#pragma unroll
    for (int j = 0; j < 32; ++j) acc[j] = sbn1[j];
#pragma unroll
    for (int k = 0; k < 48; ++k) {
        float xk = x[k];
        const float4* w4 = (const float4*)(sWn1 + k * 32);
#pragma unroll
        for (int q = 0; q < 8; ++q) {
            float4 w = w4[q];
            acc[4 * q + 0] = fmaf(xk, w.x, acc[4 * q + 0]);
            acc[4 * q + 1] = fmaf(xk, w.y, acc[4 * q + 1]);
            acc[4 * q + 2] = fmaf(xk, w.z, acc[4 * q + 2]);
            acc[4 * q + 3] = fmaf(xk, w.w, acc[4 * q + 3]);
        }
    }
    float t[32];
#pragma unroll
    for (int j = 0; j < 32; ++j) t[j] = ftanh(acc[j]);

    float acc2[16];
#pragma unroll
    for (int j = 0; j < 16; ++j) acc2[j] = sbn2[j];
#pragma unroll
    for (int k = 0; k < 32; ++k) {
        float xk = t[k];
        const float4* w4 = (const float4*)(sWn2 + k * 16);
#pragma unroll
        for (int q = 0; q < 4; ++q) {
            float4 w = w4[q];
            acc2[4 * q + 0] = fmaf(xk, w.x, acc2[4 * q + 0]);
            acc2[4 * q + 1] = fmaf(xk, w.y, acc2[4 * q + 1]);
            acc2[4 * q + 2] = fmaf(xk, w.z, acc2[4 * q + 2]);
            acc2[4 * q + 3] = fmaf(xk, w.w, acc2[4 * q + 3]);
        }
    }

    float hn[16];
    float mean = 0.0f;
#pragma unroll
    for (int j = 0; j < 16; ++j) { hn[j] = hv[j] + acc2[j]; mean += hn[j]; }
    mean *= (1.0f / 16.0f);
    float var = 0.0f;
#pragma unroll
    for (int j = 0; j < 16; ++j) { float d = hn[j] - mean; var = fmaf(d, d, var); }
    var *= (1.0f / 16.0f);
    float stdv = __builtin_amdgcn_sqrtf(var + 1e-5f);
    float sc = __builtin_amdgcn_rsqf(stdv);   // (var+eps)^(-1/4)

#pragma unroll
    for (int j = 0; j < 16; ++j) {
        h_out[(size_t)i * 16 + j] = hn[j] * sc * msk + hv[j] * (1.0f - msk);
    }
}

extern "C" void kernel_launch(void* const* d_in, const int* in_sizes, int n_in,
                              void* d_out, int out_size, void* d_ws, size_t ws_size,
                              hipStream_t stream) {
    const int*   edge_index = (const int*)d_in[0];
    const float* coord      = (const float*)d_in[1];
    const float* h          = (const float*)d_in[2];
    const float* fire       = (const float*)d_in[3];
    const float* Wm1 = (const float*)d_in[4];
    const float* bm1 = (const float*)d_in[5];
    const float* Wm2 = (const float*)d_in[6];
    const float* bm2 = (const float*)d_in[7];
    const float* Wc1 = (const float*)d_in[8];
    const float* bc1 = (const float*)d_in[9];
    const float* Wc2 = (const float*)d_in[10];
    const float* Wn1 = (const float*)d_in[11];
    const float* bn1 = (const float*)d_in[12];
    const float* Wn2 = (const float*)d_in[13];
    const float* bn2 = (const float*)d_in[14];

    const int E = in_sizes[0] / 2;
    const int N = in_sizes[1] / 3;
    const int* row = edge_index;
    const int* col = edge_index + E;

    // ws layout: num 3N f32 | agg 32N f32 | cnth N i32 | startA N i32 |
    //            bsum 256 i32 | wp 1568 u32 | rc E i32
    float*    ws     = (float*)d_ws;
    float*    num    = ws;
    float*    agg    = ws + (size_t)N * 3;
    int*      cnth   = (int*)(ws + (size_t)N * 35);
    int*      startA = cnth + N;
    int*      bsum   = startA + N;
    unsigned* wp     = (unsigned*)(bsum + 256);
    int*      rc     = (int*)(wp + 1568);

    float* out_coord = (float*)d_out;
    float* out_h     = (float*)d_out + (size_t)N * 3;

    const int eb = (E + THREADS - 1) / THREADS;
    const int nb = (N + THREADS - 1) / THREADS;

    const size_t need_sorted =
        ((size_t)N * 37 + 256 + 1568 + (size_t)E) * sizeof(float) + (1u << 20);

    if (ws_size >= need_sorted && N <= 65535) {
        // ---- one-time CSR build + weight packing ----
        (void)hipMemsetAsync(d_ws, 0, (size_t)N * 36 * sizeof(float), stream);
        pack_weights<<<7, THREADS, 0, stream>>>(Wm1, Wm2, Wc1, wp);
        hist_kernel<<<eb, THREADS, 0, stream>>>(row, cnth, E, N);
        scan_blocks<<<nb, THREADS, 0, stream>>>(cnth, startA, bsum, N);
        scan_bsums<<<1, THREADS, 0, stream>>>(bsum, nb);
        scan_add<<<nb, THREADS, 0, stream>>>(startA, bsum, N);
        scatter_rc_kernel<<<eb, THREADS, 0, stream>>>(row, col, startA, rc, E, N);

        edge_kernel_sorted<<<eb, THREADS, 0, stream>>>(rc, coord, h,
            wp, bm1, bm2, bc1, Wc2, num, agg, E, N);
        node_kernel<<<nb, THREADS, 0, stream>>>(coord, h, num, agg, cnth, fire,
            Wn1, bn1, Wn2, bn2, out_coord, out_h, N);

        (void)hipMemsetAsync(num, 0, (size_t)N * 35 * sizeof(float), stream);
        edge_kernel_sorted<<<eb, THREADS, 0, stream>>>(rc, out_coord, out_h,
            wp, bm1, bm2, bc1, Wc2, num, agg, E, N);
        node_kernel<<<nb, THREADS, 0, stream>>>(out_coord, out_h, num, agg, cnth, fire + N,
            Wn1, bn1, Wn2, bn2, out_coord, out_h, N);
    } else {
        // ---- fallback: proven round-1 atomic path (7.2 MB) ----
        (void)hipMemsetAsync(d_ws, 0, (size_t)N * 36 * sizeof(float), stream);
        hist_kernel<<<eb, THREADS, 0, stream>>>(row, cnth, E, N);

        edge_kernel_naive<<<eb, THREADS, 0, stream>>>(row, col, coord, h,
            Wm1, bm1, Wm2, bm2, Wc1, bc1, Wc2, num, agg, E, N);
        node_kernel<<<nb, THREADS, 0, stream>>>(coord, h, num, agg, cnth, fire,
            Wn1, bn1, Wn2, bn2, out_coord, out_h, N);

        (void)hipMemsetAsync(num, 0, (size_t)N * 35 * sizeof(float), stream);
        edge_kernel_naive<<<eb, THREADS, 0, stream>>>(row, col, out_coord, out_h,
            Wm1, bm1, Wm2, bm2, Wc1, bc1, Wc2, num, agg, E, N);
        node_kernel<<<nb, THREADS, 0, stream>>>(out_coord, out_h, num, agg, cnth, fire + N,
            Wn1, bn1, Wn2, bn2, out_coord, out_h, N);
    }
}